// Round 1
// baseline (566.583 us; speedup 1.0000x reference)
//
#include <hip/hip_runtime.h>
#include <math.h>

// Problem constants
#define B_      8
#define T_      2048
#define DIMX    512
#define DM      128
#define DINNER  256
#define NSTATE  16
#define HDIM    64
#define NH      4
#define CONVDIM 288     // DINNER + 2*NSTATE
#define PROJ    548     // DINNER + CONVDIM + NH
#define KCONV   4
#define LLAYERS 2
#define QCH     128     // chunk length
#define NC      (T_/QCH)  // 16 chunks
#define EPSF    1e-5f
#define MTOK    (B_*T_)   // 16384

// ---- workspace layout (float offsets) ----
#define OFF_H      0u               // 16384*128   = 2097152
#define OFF_PROJ   2097152u         // 16384*548   = 8978432
#define OFF_HBC    11075584u        // 16384*288   = 4718592
#define OFF_Y      15794176u        // 16384*256   = 4194304
#define OFF_DTP    19988480u        // 16384*4     = 65536
#define OFF_CUM    20054016u        // 16384*4     = 65536
#define OFF_Z      20119552u        // 512*1024    = 524288
#define OFF_SPREV  20643840u        // 512*1024    = 524288
#define OFF_DEC    21168128u        // 512
#define OFF_PART   21168640u        // 8*128*128   = 131072
// total 21299712 floats = 85.2 MB

// ============ h = x @ in_w + in_b  (16384x512 @ 512x128) ============
__global__ __launch_bounds__(256) void k_in_gemm(
    const float* __restrict__ x, const float* __restrict__ w,
    const float* __restrict__ bias, float* __restrict__ h)
{
    __shared__ float xs[16 * 512];  // 32 KB
    const int m0 = blockIdx.x * 16;
    const int tid = threadIdx.x;
    for (int e = tid; e < 16 * 512; e += 256) xs[e] = x[m0 * 512 + e];
    __syncthreads();
    const int c  = tid & 127;
    const int rg = tid >> 7;   // 0..1 -> rows rg*8 .. rg*8+7
    float acc[8];
#pragma unroll
    for (int r = 0; r < 8; ++r) acc[r] = 0.f;
    for (int k = 0; k < 512; k += 4) {
        const float w0 = w[(k + 0) * 128 + c];
        const float w1 = w[(k + 1) * 128 + c];
        const float w2 = w[(k + 2) * 128 + c];
        const float w3 = w[(k + 3) * 128 + c];
#pragma unroll
        for (int r = 0; r < 8; ++r) {
            const float4 xv = *(const float4*)&xs[(rg * 8 + r) * 512 + k];
            acc[r] += xv.x * w0 + xv.y * w1 + xv.z * w2 + xv.w * w3;
        }
    }
    const float bc = bias[c];
#pragma unroll
    for (int r = 0; r < 8; ++r)
        h[(m0 + rg * 8 + r) * 128 + c] = acc[r] + bc;
}

// ===== per-token rmsnorm + proj = hn @ inproj_w  (16 tokens / block) =====
__global__ __launch_bounds__(256) void k_norm_inproj(
    const float* __restrict__ h, const float* __restrict__ nw,
    const float* __restrict__ W, float* __restrict__ proj)
{
    __shared__ float ht[16 * 128];
    __shared__ float red[256];
    __shared__ float rstd[16];
    const int m0 = blockIdx.x * 16;
    const int tid = threadIdx.x;
    for (int e = tid; e < 2048; e += 256) ht[e] = h[m0 * 128 + e];
    __syncthreads();
    {
        const int tg = tid >> 4, j0 = tid & 15;
        float p = 0.f;
#pragma unroll
        for (int k = 0; k < 8; ++k) { float v = ht[tg * 128 + j0 + 16 * k]; p += v * v; }
        red[tid] = p;
    }
    __syncthreads();
    if (tid < 16) {
        float s = 0.f;
#pragma unroll
        for (int q = 0; q < 16; ++q) s += red[tid * 16 + q];
        rstd[tid] = rsqrtf(s * (1.f / 128.f) + EPSF);
    }
    __syncthreads();
    for (int e = tid; e < 2048; e += 256) {
        const int i = e >> 7, j = e & 127;
        ht[e] = ht[e] * rstd[i] * nw[j];
    }
    __syncthreads();
    // GEMM: 16 x 548, k-outer, 16-row register block so W is read once per (k,c)
    for (int c = tid; c < PROJ; c += 256) {
        float acc[16];
#pragma unroll
        for (int i = 0; i < 16; ++i) acc[i] = 0.f;
        for (int k = 0; k < 128; k += 4) {
            const float w0 = W[(k + 0) * PROJ + c];
            const float w1 = W[(k + 1) * PROJ + c];
            const float w2 = W[(k + 2) * PROJ + c];
            const float w3 = W[(k + 3) * PROJ + c];
#pragma unroll
            for (int i = 0; i < 16; ++i) {
                const float4 hv = *(const float4*)&ht[i * 128 + k];
                acc[i] += hv.x * w0 + hv.y * w1 + hv.z * w2 + hv.w * w3;
            }
        }
#pragma unroll
        for (int i = 0; i < 16; ++i) proj[(m0 + i) * PROJ + c] = acc[i];
    }
}

// ===== dt = softplus(raw + bias); a = dt*A; per-chunk inclusive cumsum =====
__global__ __launch_bounds__(128) void k_dtprep(
    const float* __restrict__ proj, const float* __restrict__ A_log,
    const float* __restrict__ dt_bias, float* __restrict__ dtp,
    float* __restrict__ cum, int l)
{
    __shared__ float sc[128];
    const int bid = blockIdx.x;
    const int c = bid & (NC - 1);
    const int hh = (bid / NC) & (NH - 1);
    const int b = bid / (NC * NH);
    const int t = threadIdx.x;
    const int m = b * T_ + c * QCH + t;
    const float Ah = -expf(A_log[l * NH + hh]);
    const float raw = proj[m * PROJ + DINNER + CONVDIM + hh] + dt_bias[l * NH + hh];
    const float dtv = (raw > 20.f) ? raw : log1pf(expf(raw));
    sc[t] = dtv * Ah;
    __syncthreads();
    for (int off = 1; off < 128; off <<= 1) {
        const float v = (t >= off) ? sc[t - off] : 0.f;
        __syncthreads();
        sc[t] += v;
        __syncthreads();
    }
    dtp[m * NH + hh] = dtv;
    cum[m * NH + hh] = sc[t];
}

// ===== depthwise causal conv (K=4) + silu =====
__global__ __launch_bounds__(256) void k_conv(
    const float* __restrict__ proj, const float* __restrict__ cw,
    const float* __restrict__ cb, float* __restrict__ hbc, int l)
{
    const int e = blockIdx.x * 256 + threadIdx.x;
    if (e >= MTOK * CONVDIM) return;
    const int m = e / CONVDIM;
    const int cch = e - m * CONVDIM;
    const int b = m >> 11;          // / 2048
    const int t = m & (T_ - 1);
    const float* wp = cw + (l * CONVDIM + cch) * KCONV;
    float acc = cb[l * CONVDIM + cch];
#pragma unroll
    for (int k = 0; k < KCONV; ++k) {
        const int tt = t - (KCONV - 1) + k;
        if (tt >= 0) acc += proj[(b * T_ + tt) * PROJ + DINNER + cch] * wp[k];
    }
    hbc[m * CONVDIM + cch] = acc / (1.f + __expf(-acc));
}

// ===== intra-chunk SSD: y_intra + D*x, and chunk state contribution Z =====
__global__ __launch_bounds__(256) void k_ssd_intra(
    const float* __restrict__ hbc, const float* __restrict__ dtp,
    const float* __restrict__ cum, const float* __restrict__ Dvec,
    float* __restrict__ ybuf, float* __restrict__ zbuf,
    float* __restrict__ dec, int l)
{
    __shared__ float xls[QCH * 64];    // 32 KB, [s][p]
    __shared__ float bls[QCH * 17];    // padded stride 17
    __shared__ float cls[QCH * 17];
    __shared__ float cumls[QCH];
    __shared__ float dtls[QCH];
    __shared__ float wq[QCH];
    __shared__ float gls[4 * QCH];     // per-wave G row
    const int bid = blockIdx.x;
    const int c = bid & (NC - 1);
    const int hh = (bid / NC) & (NH - 1);
    const int b = bid / (NC * NH);
    const int m0 = b * T_ + c * QCH;
    const int tid = threadIdx.x;

    for (int e = tid; e < QCH * 64; e += 256) {
        const int s = e >> 6, p = e & 63;
        xls[e] = hbc[(m0 + s) * CONVDIM + hh * 64 + p];
    }
    for (int e = tid; e < QCH * 16; e += 256) {
        const int s = e >> 4, n = e & 15;
        bls[s * 17 + n] = hbc[(m0 + s) * CONVDIM + DINNER + n];
        cls[s * 17 + n] = hbc[(m0 + s) * CONVDIM + DINNER + NSTATE + n];
    }
    if (tid < QCH) {
        dtls[tid] = dtp[(m0 + tid) * NH + hh];
        cumls[tid] = cum[(m0 + tid) * NH + hh];
    }
    __syncthreads();

    const int lane = tid & 63;
    const int w = tid >> 6;
    const float Dh = Dvec[l * NH + hh];

    for (int tb = 0; tb < 32; ++tb) {
        const int t = tb * 4 + w;   // wave-uniform t
        float cn[16];
#pragma unroll
        for (int n = 0; n < 16; ++n) cn[n] = cls[t * 17 + n];
        const float cumt = cumls[t];
#pragma unroll
        for (int rep = 0; rep < 2; ++rep) {
            const int s = lane + rep * 64;
            if (s <= t) {
                float dot = 0.f;
#pragma unroll
                for (int n = 0; n < 16; ++n) dot += cn[n] * bls[s * 17 + n];
                gls[w * QCH + s] = __expf(cumt - cumls[s]) * dtls[s] * dot;
            }
        }
        __syncthreads();   // uniform: 32 barriers per wave
        float acc = Dh * xls[t * 64 + lane];
        for (int s = 0; s <= t; ++s)
            acc += gls[w * QCH + s] * xls[s * 64 + lane];
        ybuf[(m0 + t) * DINNER + hh * 64 + lane] = acc;
    }

    // Z[p][n] = sum_s exp(cum_last - cum_s) * dt_s * x_s[p] * B_s[n]
    if (tid < QCH) wq[tid] = __expf(cumls[QCH - 1] - cumls[tid]) * dtls[tid];
    __syncthreads();
    {
        const int p = tid & 63;
        const int nb = tid >> 6;
        float za0 = 0.f, za1 = 0.f, za2 = 0.f, za3 = 0.f;
        for (int s = 0; s < QCH; ++s) {
            const float xw = wq[s] * xls[s * 64 + p];
            za0 += xw * bls[s * 17 + nb * 4 + 0];
            za1 += xw * bls[s * 17 + nb * 4 + 1];
            za2 += xw * bls[s * 17 + nb * 4 + 2];
            za3 += xw * bls[s * 17 + nb * 4 + 3];
        }
        float4 zz; zz.x = za0; zz.y = za1; zz.z = za2; zz.w = za3;
        *(float4*)(zbuf + bid * 1024 + p * 16 + nb * 4) = zz;
    }
    if (tid == 0) dec[bid] = __expf(cumls[QCH - 1]);
}

// ===== inter-chunk state scan (16 sequential chunks, 32 blocks) =====
__global__ __launch_bounds__(256) void k_state_scan(
    const float* __restrict__ zbuf, const float* __restrict__ dec,
    float* __restrict__ sprev)
{
    const int bh = blockIdx.x;
    const int tid = threadIdx.x;
    float4 S; S.x = 0.f; S.y = 0.f; S.z = 0.f; S.w = 0.f;
    for (int c = 0; c < NC; ++c) {
        const int idx = (bh * NC + c) * 1024 + tid * 4;
        *(float4*)(sprev + idx) = S;
        const float d = dec[bh * NC + c];
        const float4 z = *(const float4*)(zbuf + idx);
        S.x = S.x * d + z.x; S.y = S.y * d + z.y;
        S.z = S.z * d + z.z; S.w = S.w * d + z.w;
    }
}

// ===== inter-chunk y correction: y += exp(cum_t) * C_t . S_prev =====
__global__ __launch_bounds__(256) void k_ssd_inter(
    const float* __restrict__ hbc, const float* __restrict__ cum,
    const float* __restrict__ sprev, float* __restrict__ ybuf)
{
    __shared__ float sp[64 * 17];
    __shared__ float cls[QCH * 17];
    __shared__ float cumls[QCH];
    const int bid = blockIdx.x;
    const int c = bid & (NC - 1);
    const int hh = (bid / NC) & (NH - 1);
    const int b = bid / (NC * NH);
    const int m0 = b * T_ + c * QCH;
    const int tid = threadIdx.x;
    {
        const float4 z = *(const float4*)(sprev + bid * 1024 + tid * 4);
        const int p = tid >> 2;
        const int n0 = (tid & 3) * 4;
        sp[p * 17 + n0 + 0] = z.x; sp[p * 17 + n0 + 1] = z.y;
        sp[p * 17 + n0 + 2] = z.z; sp[p * 17 + n0 + 3] = z.w;
    }
    for (int e = tid; e < QCH * 16; e += 256) {
        const int t = e >> 4, n = e & 15;
        cls[t * 17 + n] = hbc[(m0 + t) * CONVDIM + DINNER + NSTATE + n];
    }
    if (tid < QCH) cumls[tid] = cum[(m0 + tid) * NH + hh];
    __syncthreads();
    const int p = tid & 63;
    const int tq = tid >> 6;   // wave-uniform
    for (int pass = 0; pass < 32; ++pass) {
        const int t = pass * 4 + tq;
        float dot = 0.f;
#pragma unroll
        for (int n = 0; n < 16; ++n) dot += cls[t * 17 + n] * sp[p * 17 + n];
        ybuf[(m0 + t) * DINNER + hh * 64 + p] += __expf(cumls[t]) * dot;
    }
}

// ===== gated rmsnorm + outproj + residual (in-place h update) =====
__global__ __launch_bounds__(256) void k_gnorm_outproj(
    const float* __restrict__ ybuf, const float* __restrict__ proj,
    const float* __restrict__ gw, const float* __restrict__ W,
    float* __restrict__ h)
{
    __shared__ float vls[16 * DINNER];   // 16 KB
    __shared__ float red[256];
    __shared__ float rstd[16];
    const int m0 = blockIdx.x * 16;
    const int tid = threadIdx.x;
    for (int e = tid; e < 16 * DINNER; e += 256) {
        const int i = e >> 8, j = e & 255;
        const float g = proj[(m0 + i) * PROJ + j];
        const float yv = ybuf[(m0 + i) * DINNER + j];
        vls[e] = yv * (g / (1.f + __expf(-g)));
    }
    __syncthreads();
    {
        const int tg = tid >> 4, j0 = tid & 15;
        float pacc = 0.f;
#pragma unroll
        for (int k = 0; k < 16; ++k) { const float v = vls[tg * 256 + j0 + 16 * k]; pacc += v * v; }
        red[tid] = pacc;
    }
    __syncthreads();
    if (tid < 16) {
        float s = 0.f;
#pragma unroll
        for (int q = 0; q < 16; ++q) s += red[tid * 16 + q];
        rstd[tid] = rsqrtf(s * (1.f / 256.f) + EPSF);
    }
    __syncthreads();
    for (int e = tid; e < 16 * DINNER; e += 256) {
        const int i = e >> 8, j = e & 255;
        vls[e] = vls[e] * rstd[i] * gw[j];
    }
    __syncthreads();
    const int d = tid & 127;
    const int rg = tid >> 7;
    float acc[8];
#pragma unroll
    for (int r = 0; r < 8; ++r) acc[r] = h[(m0 + rg * 8 + r) * DM + d];  // residual
    for (int k = 0; k < DINNER; k += 4) {
        const float w0 = W[(k + 0) * DM + d];
        const float w1 = W[(k + 1) * DM + d];
        const float w2 = W[(k + 2) * DM + d];
        const float w3 = W[(k + 3) * DM + d];
#pragma unroll
        for (int r = 0; r < 8; ++r) {
            const float4 v = *(const float4*)&vls[(rg * 8 + r) * 256 + k];
            acc[r] += v.x * w0 + v.y * w1 + v.z * w2 + v.w * w3;
        }
    }
#pragma unroll
    for (int r = 0; r < 8; ++r) h[(m0 + rg * 8 + r) * DM + d] = acc[r];
}

// ===== final rmsnorm + partial mean-pool =====
__global__ __launch_bounds__(256) void k_finalnorm_pool(
    const float* __restrict__ h, const float* __restrict__ nfw,
    float* __restrict__ part)
{
    __shared__ float ht[2048];
    __shared__ float red[256];
    __shared__ float rstd[16];
    __shared__ float padd[256];
    const int tile = blockIdx.x & 127;
    const int b = blockIdx.x >> 7;
    const int m0 = b * T_ + tile * 16;
    const int tid = threadIdx.x;
    for (int e = tid; e < 2048; e += 256) ht[e] = h[m0 * DM + e];
    __syncthreads();
    {
        const int tg = tid >> 4, j0 = tid & 15;
        float p = 0.f;
#pragma unroll
        for (int k = 0; k < 8; ++k) { const float v = ht[tg * 128 + j0 + 16 * k]; p += v * v; }
        red[tid] = p;
    }
    __syncthreads();
    if (tid < 16) {
        float s = 0.f;
#pragma unroll
        for (int q = 0; q < 16; ++q) s += red[tid * 16 + q];
        rstd[tid] = rsqrtf(s * (1.f / 128.f) + EPSF);
    }
    __syncthreads();
    const int d = tid & 127, half = tid >> 7;
    float ps = 0.f;
#pragma unroll
    for (int i0 = 0; i0 < 8; ++i0) { const int i = half + 2 * i0; ps += ht[i * 128 + d] * rstd[i]; }
    padd[tid] = ps;
    __syncthreads();
    if (tid < 128) part[(b * 128 + tile) * 128 + tid] = (padd[tid] + padd[128 + tid]) * nfw[tid];
}

// ===== pooled reduce + head GEMM =====
__global__ __launch_bounds__(256) void k_head(
    const float* __restrict__ part, const float* __restrict__ ow,
    const float* __restrict__ ob, float* __restrict__ out)
{
    __shared__ float pooled[128];
    const int b = blockIdx.x;
    const int tid = threadIdx.x;
    if (tid < 128) {
        float s = 0.f;
        for (int tile = 0; tile < 128; ++tile) s += part[(b * 128 + tile) * 128 + tid];
        pooled[tid] = s * (1.f / (float)T_);
    }
    __syncthreads();
    for (int o = tid; o < DIMX; o += 256) {
        float acc = ob[o];
#pragma unroll 4
        for (int d = 0; d < 128; ++d) acc += pooled[d] * ow[d * DIMX + o];
        out[b * DIMX + o] = acc;
    }
}

extern "C" void kernel_launch(void* const* d_in, const int* in_sizes, int n_in,
                              void* d_out, int out_size, void* d_ws, size_t ws_size,
                              hipStream_t stream)
{
    const float* x         = (const float*)d_in[0];
    const float* in_w      = (const float*)d_in[1];
    const float* in_b      = (const float*)d_in[2];
    const float* norm_w    = (const float*)d_in[3];
    const float* inproj_w  = (const float*)d_in[4];
    const float* conv_w    = (const float*)d_in[5];
    const float* conv_b    = (const float*)d_in[6];
    const float* A_log     = (const float*)d_in[7];
    const float* Dvec      = (const float*)d_in[8];
    const float* dt_bias   = (const float*)d_in[9];
    const float* gnorm_w   = (const float*)d_in[10];
    const float* outproj_w = (const float*)d_in[11];
    const float* normf_w   = (const float*)d_in[12];
    const float* out_w     = (const float*)d_in[13];
    const float* out_b     = (const float*)d_in[14];

    float* ws    = (float*)d_ws;
    float* h     = ws + OFF_H;
    float* proj  = ws + OFF_PROJ;
    float* hbc   = ws + OFF_HBC;
    float* ybuf  = ws + OFF_Y;
    float* dtp   = ws + OFF_DTP;
    float* cumb  = ws + OFF_CUM;
    float* zbuf  = ws + OFF_Z;
    float* sprev = ws + OFF_SPREV;
    float* dec   = ws + OFF_DEC;
    float* part  = ws + OFF_PART;

    k_in_gemm<<<MTOK / 16, 256, 0, stream>>>(x, in_w, in_b, h);

    for (int l = 0; l < LLAYERS; ++l) {
        k_norm_inproj<<<MTOK / 16, 256, 0, stream>>>(
            h, norm_w + l * DM, inproj_w + l * DM * PROJ, proj);
        k_dtprep<<<B_ * NH * NC, 128, 0, stream>>>(proj, A_log, dt_bias, dtp, cumb, l);
        k_conv<<<(MTOK * CONVDIM) / 256, 256, 0, stream>>>(proj, conv_w, conv_b, hbc, l);
        k_ssd_intra<<<B_ * NH * NC, 256, 0, stream>>>(hbc, dtp, cumb, Dvec, ybuf, zbuf, dec, l);
        k_state_scan<<<B_ * NH, 256, 0, stream>>>(zbuf, dec, sprev);
        k_ssd_inter<<<B_ * NH * NC, 256, 0, stream>>>(hbc, cumb, sprev, ybuf);
        k_gnorm_outproj<<<MTOK / 16, 256, 0, stream>>>(
            ybuf, proj, gnorm_w + l * DINNER, outproj_w + l * DINNER * DM, h);
    }

    k_finalnorm_pool<<<B_ * (T_ / 16), 256, 0, stream>>>(h, normf_w, part);
    k_head<<<B_, 256, 0, stream>>>(part, out_w, out_b, (float*)d_out);
}

// Round 2
// 428.309 us; speedup vs baseline: 1.3228x; 1.3228x over previous
//
#include <hip/hip_runtime.h>
#include <math.h>

typedef unsigned short ushort_t;
typedef unsigned int uint_t;

// Problem constants
#define B_      8
#define T_      2048
#define DIMX    512
#define DM      128
#define DINNER  256
#define NSTATE  16
#define HDIM    64
#define NH      4
#define CONVDIM 288     // DINNER + 2*NSTATE
#define PROJ    548     // DINNER + CONVDIM + NH
#define KCONV   4
#define LLAYERS 2
#define QCH     128     // chunk length
#define NC      (T_/QCH)  // 16 chunks
#define EPSF    1e-5f
#define MTOK    (B_*T_)   // 16384

// ---- workspace layout (float offsets) ----
#define OFF_H      0u               // 16384*128   = 2097152
#define OFF_PROJ   2097152u         // 16384*548   = 8978432
#define OFF_HBC    11075584u        // 16384*288   = 4718592
#define OFF_Y      15794176u        // 16384*256   = 4194304
#define OFF_DTP    19988480u        // 16384*4     = 65536
#define OFF_CUM    20054016u        // 16384*4     = 65536
#define OFF_Z      20119552u        // 512*1024    = 524288
#define OFF_SPREV  20643840u        // 512*1024    = 524288
#define OFF_DEC    21168128u        // 512
#define OFF_PART   21168640u        // 8*128*128   = 131072
#define OFF_BF     21299712u        // bf16 scratch (hn OR v): 2097152 floats
#define OFF_WTIN   23396864u        // 128x512 bf16 = 32768 floats
#define OFF_WTINP  23429632u        // 2x576x128 bf16 = 73728 floats
#define OFF_WTOUT  23503360u        // 2x128x256 bf16 = 32768 floats
// end 23536128 floats = 94.1 MB

__device__ __forceinline__ ushort_t f2b(float f) {
    uint_t u = __builtin_bit_cast(uint_t, f);
    return (ushort_t)((u + 0x7FFFu + ((u >> 16) & 1u)) >> 16);
}

typedef short bf8 __attribute__((ext_vector_type(8)));
typedef float f4v __attribute__((ext_vector_type(4)));

// ===== weight transpose + bf16 convert: W[K x N] fp32 -> Wt[Npad x K] bf16 =====
__global__ __launch_bounds__(256) void k_wt(
    const float* __restrict__ W, ushort_t* __restrict__ Wt,
    int K, int N, int Npad)
{
    __shared__ float tile[64][65];
    const int k0 = blockIdx.x * 64, n0 = blockIdx.y * 64;
    const int tid = threadIdx.x;
#pragma unroll
    for (int it = 0; it < 16; ++it) {
        const int e = it * 256 + tid;
        const int kk = e >> 6, nn = e & 63;
        tile[kk][nn] = (n0 + nn < N) ? W[(k0 + kk) * N + (n0 + nn)] : 0.f;
    }
    __syncthreads();
#pragma unroll
    for (int it = 0; it < 16; ++it) {
        const int e = it * 256 + tid;
        const int nn = e >> 6, kk = e & 63;
        Wt[(n0 + nn) * K + k0 + kk] = f2b(tile[kk][nn]);
    }
}

// ===== MFMA GEMM: C[M x NGUARD] (ld LDC) = A[M x KTOT] @ Bt^T, 64x64 tile =====
// EPI: 0 = plain, 1 = +bias(aux[col]), 2 = += C in place (residual)
template<int KTOT, int LDC, int NGUARD, int EPI, bool ABF16>
__global__ __launch_bounds__(256) void k_gemm(
    const void* __restrict__ Ap, const ushort_t* __restrict__ Bt,
    const float* __restrict__ aux, float* __restrict__ C)
{
    __shared__ ushort_t Als[64 * 136];
    __shared__ ushort_t Bls[64 * 136];
    const int m0 = blockIdx.x * 64, n0 = blockIdx.y * 64;
    const int tid = threadIdx.x;
    const int lane = tid & 63, w = tid >> 6;
    const int wm = (w >> 1) * 32, wn = (w & 1) * 32;
    const int r16 = lane & 15, q8 = (lane >> 4) * 8;

    f4v acc[2][2];
#pragma unroll
    for (int i = 0; i < 2; ++i)
#pragma unroll
        for (int j = 0; j < 2; ++j) acc[i][j] = (f4v)0.f;

    for (int kc = 0; kc < KTOT; kc += 128) {
        if constexpr (ABF16) {
            const ushort_t* A = (const ushort_t*)Ap;
#pragma unroll
            for (int i = 0; i < 4; ++i) {
                const int e = i * 2048 + tid * 8;
                const int r = e >> 7, c = e & 127;
                *(uint4*)&Als[r * 136 + c] = *(const uint4*)&A[(m0 + r) * KTOT + kc + c];
            }
        } else {
            const float* A = (const float*)Ap;
#pragma unroll
            for (int i = 0; i < 4; ++i) {
                const int e = i * 2048 + tid * 8;
                const int r = e >> 7, c = e & 127;
                const float4 f0 = *(const float4*)&A[(m0 + r) * KTOT + kc + c];
                const float4 f1 = *(const float4*)&A[(m0 + r) * KTOT + kc + c + 4];
                uint4 pk;
                pk.x = (uint_t)f2b(f0.x) | ((uint_t)f2b(f0.y) << 16);
                pk.y = (uint_t)f2b(f0.z) | ((uint_t)f2b(f0.w) << 16);
                pk.z = (uint_t)f2b(f1.x) | ((uint_t)f2b(f1.y) << 16);
                pk.w = (uint_t)f2b(f1.z) | ((uint_t)f2b(f1.w) << 16);
                *(uint4*)&Als[r * 136 + c] = pk;
            }
        }
#pragma unroll
        for (int i = 0; i < 4; ++i) {
            const int e = i * 2048 + tid * 8;
            const int r = e >> 7, c = e & 127;
            *(uint4*)&Bls[r * 136 + c] = *(const uint4*)&Bt[(n0 + r) * KTOT + kc + c];
        }
        __syncthreads();
#pragma unroll
        for (int kk = 0; kk < 128; kk += 32) {
            const bf8 a0 = *(const bf8*)&Als[(wm + r16) * 136 + kk + q8];
            const bf8 a1 = *(const bf8*)&Als[(wm + 16 + r16) * 136 + kk + q8];
            const bf8 b0 = *(const bf8*)&Bls[(wn + r16) * 136 + kk + q8];
            const bf8 b1 = *(const bf8*)&Bls[(wn + 16 + r16) * 136 + kk + q8];
            acc[0][0] = __builtin_amdgcn_mfma_f32_16x16x32_bf16(a0, b0, acc[0][0], 0, 0, 0);
            acc[0][1] = __builtin_amdgcn_mfma_f32_16x16x32_bf16(a0, b1, acc[0][1], 0, 0, 0);
            acc[1][0] = __builtin_amdgcn_mfma_f32_16x16x32_bf16(a1, b0, acc[1][0], 0, 0, 0);
            acc[1][1] = __builtin_amdgcn_mfma_f32_16x16x32_bf16(a1, b1, acc[1][1], 0, 0, 0);
        }
        __syncthreads();
    }
    const int q4 = (lane >> 4) * 4;
#pragma unroll
    for (int i = 0; i < 2; ++i)
#pragma unroll
        for (int j = 0; j < 2; ++j)
#pragma unroll
            for (int r = 0; r < 4; ++r) {
                const int grow = m0 + wm + i * 16 + q4 + r;
                const int gcol = n0 + wn + j * 16 + r16;
                if (NGUARD == 0 || gcol < NGUARD) {
                    float v = acc[i][j][r];
                    if (EPI == 1) v += aux[gcol];
                    if (EPI == 2) v += C[grow * LDC + gcol];
                    C[grow * LDC + gcol] = v;
                }
            }
}

// ===== rmsnorm: h (fp32) -> hn (bf16), one token per wave-quarter group =====
__global__ __launch_bounds__(256) void k_rmsnorm(
    const float* __restrict__ h, const float* __restrict__ nw,
    ushort_t* __restrict__ hnb)
{
    const int tk = blockIdx.x * 4 + (threadIdx.x >> 6);
    const int lane = threadIdx.x & 63;
    const float2 v = *(const float2*)&h[tk * 128 + lane * 2];
    float s = v.x * v.x + v.y * v.y;
#pragma unroll
    for (int off = 32; off; off >>= 1) s += __shfl_xor(s, off);
    const float rs = rsqrtf(s * (1.f / 128.f) + EPSF);
    const float a = v.x * rs * nw[lane * 2];
    const float b = v.y * rs * nw[lane * 2 + 1];
    ((uint_t*)hnb)[tk * 64 + lane] = (uint_t)f2b(a) | ((uint_t)f2b(b) << 16);
}

// ===== gated rmsnorm: v = rmsnorm(y * silu(gate)) * gw -> bf16 =====
__global__ __launch_bounds__(256) void k_gnorm(
    const float* __restrict__ y, const float* __restrict__ proj,
    const float* __restrict__ gw, ushort_t* __restrict__ vb)
{
    const int tok = blockIdx.x * 4 + (threadIdx.x >> 6);
    const int lane = threadIdx.x & 63;
    const float4 yv = *(const float4*)&y[tok * 256 + lane * 4];
    const float4 g = *(const float4*)&proj[tok * PROJ + lane * 4];
    float4 v;
    v.x = yv.x * (g.x / (1.f + __expf(-g.x)));
    v.y = yv.y * (g.y / (1.f + __expf(-g.y)));
    v.z = yv.z * (g.z / (1.f + __expf(-g.z)));
    v.w = yv.w * (g.w / (1.f + __expf(-g.w)));
    float s = v.x * v.x + v.y * v.y + v.z * v.z + v.w * v.w;
#pragma unroll
    for (int off = 32; off; off >>= 1) s += __shfl_xor(s, off);
    const float rs = rsqrtf(s * (1.f / 256.f) + EPSF);
    const float4 w4 = *(const float4*)&gw[lane * 4];
    uint2 pk;
    pk.x = (uint_t)f2b(v.x * rs * w4.x) | ((uint_t)f2b(v.y * rs * w4.y) << 16);
    pk.y = (uint_t)f2b(v.z * rs * w4.z) | ((uint_t)f2b(v.w * rs * w4.w) << 16);
    ((uint2*)vb)[tok * 64 + lane] = pk;
}

// ===== dt = softplus(raw + bias); per-chunk inclusive cumsum of dt*A =====
__global__ __launch_bounds__(128) void k_dtprep(
    const float* __restrict__ proj, const float* __restrict__ A_log,
    const float* __restrict__ dt_bias, float* __restrict__ dtp,
    float* __restrict__ cum, int l)
{
    __shared__ float sc[128];
    const int bid = blockIdx.x;
    const int c = bid & (NC - 1);
    const int hh = (bid / NC) & (NH - 1);
    const int b = bid / (NC * NH);
    const int t = threadIdx.x;
    const int m = b * T_ + c * QCH + t;
    const float Ah = -expf(A_log[l * NH + hh]);
    const float raw = proj[m * PROJ + DINNER + CONVDIM + hh] + dt_bias[l * NH + hh];
    const float dtv = (raw > 20.f) ? raw : log1pf(expf(raw));
    sc[t] = dtv * Ah;
    __syncthreads();
    for (int off = 1; off < 128; off <<= 1) {
        const float v = (t >= off) ? sc[t - off] : 0.f;
        __syncthreads();
        sc[t] += v;
        __syncthreads();
    }
    dtp[m * NH + hh] = dtv;
    cum[m * NH + hh] = sc[t];
}

// ===== depthwise causal conv (K=4) + silu =====
__global__ __launch_bounds__(256) void k_conv(
    const float* __restrict__ proj, const float* __restrict__ cw,
    const float* __restrict__ cb, float* __restrict__ hbc, int l)
{
    const int e = blockIdx.x * 256 + threadIdx.x;
    if (e >= MTOK * CONVDIM) return;
    const int m = e / CONVDIM;
    const int cch = e - m * CONVDIM;
    const int b = m >> 11;
    const int t = m & (T_ - 1);
    const float* wp = cw + (l * CONVDIM + cch) * KCONV;
    float acc = cb[l * CONVDIM + cch];
#pragma unroll
    for (int k = 0; k < KCONV; ++k) {
        const int tt = t - (KCONV - 1) + k;
        if (tt >= 0) acc += proj[(b * T_ + tt) * PROJ + DINNER + cch] * wp[k];
    }
    hbc[m * CONVDIM + cch] = acc / (1.f + __expf(-acc));
}

// ===== intra-chunk SSD =====
__global__ __launch_bounds__(256) void k_ssd_intra(
    const float* __restrict__ hbc, const float* __restrict__ dtp,
    const float* __restrict__ cum, const float* __restrict__ Dvec,
    float* __restrict__ ybuf, float* __restrict__ zbuf,
    float* __restrict__ dec, int l)
{
    __shared__ float xls[QCH * 64];
    __shared__ float bls[QCH * 17];
    __shared__ float cls[QCH * 17];
    __shared__ float cumls[QCH];
    __shared__ float dtls[QCH];
    __shared__ float wq[QCH];
    __shared__ float gls[4 * QCH];
    const int bid = blockIdx.x;
    const int c = bid & (NC - 1);
    const int hh = (bid / NC) & (NH - 1);
    const int b = bid / (NC * NH);
    const int m0 = b * T_ + c * QCH;
    const int tid = threadIdx.x;

    for (int e = tid; e < QCH * 64; e += 256) {
        const int s = e >> 6, p = e & 63;
        xls[e] = hbc[(m0 + s) * CONVDIM + hh * 64 + p];
    }
    for (int e = tid; e < QCH * 16; e += 256) {
        const int s = e >> 4, n = e & 15;
        bls[s * 17 + n] = hbc[(m0 + s) * CONVDIM + DINNER + n];
        cls[s * 17 + n] = hbc[(m0 + s) * CONVDIM + DINNER + NSTATE + n];
    }
    if (tid < QCH) {
        dtls[tid] = dtp[(m0 + tid) * NH + hh];
        cumls[tid] = cum[(m0 + tid) * NH + hh];
    }
    __syncthreads();

    const int lane = tid & 63;
    const int w = tid >> 6;
    const float Dh = Dvec[l * NH + hh];

    for (int tb = 0; tb < 32; ++tb) {
        const int t = tb * 4 + w;
        float cn[16];
#pragma unroll
        for (int n = 0; n < 16; ++n) cn[n] = cls[t * 17 + n];
        const float cumt = cumls[t];
#pragma unroll
        for (int rep = 0; rep < 2; ++rep) {
            const int s = lane + rep * 64;
            if (s <= t) {
                float dot = 0.f;
#pragma unroll
                for (int n = 0; n < 16; ++n) dot += cn[n] * bls[s * 17 + n];
                gls[w * QCH + s] = __expf(cumt - cumls[s]) * dtls[s] * dot;
            }
        }
        __syncthreads();
        float acc = Dh * xls[t * 64 + lane];
        for (int s = 0; s <= t; ++s)
            acc += gls[w * QCH + s] * xls[s * 64 + lane];
        ybuf[(m0 + t) * DINNER + hh * 64 + lane] = acc;
    }

    if (tid < QCH) wq[tid] = __expf(cumls[QCH - 1] - cumls[tid]) * dtls[tid];
    __syncthreads();
    {
        const int p = tid & 63;
        const int nb = tid >> 6;
        float za0 = 0.f, za1 = 0.f, za2 = 0.f, za3 = 0.f;
        for (int s = 0; s < QCH; ++s) {
            const float xw = wq[s] * xls[s * 64 + p];
            za0 += xw * bls[s * 17 + nb * 4 + 0];
            za1 += xw * bls[s * 17 + nb * 4 + 1];
            za2 += xw * bls[s * 17 + nb * 4 + 2];
            za3 += xw * bls[s * 17 + nb * 4 + 3];
        }
        float4 zz; zz.x = za0; zz.y = za1; zz.z = za2; zz.w = za3;
        *(float4*)(zbuf + bid * 1024 + p * 16 + nb * 4) = zz;
    }
    if (tid == 0) dec[bid] = __expf(cumls[QCH - 1]);
}

// ===== inter-chunk state scan =====
__global__ __launch_bounds__(256) void k_state_scan(
    const float* __restrict__ zbuf, const float* __restrict__ dec,
    float* __restrict__ sprev)
{
    const int bh = blockIdx.x;
    const int tid = threadIdx.x;
    float4 S; S.x = 0.f; S.y = 0.f; S.z = 0.f; S.w = 0.f;
    for (int c = 0; c < NC; ++c) {
        const int idx = (bh * NC + c) * 1024 + tid * 4;
        *(float4*)(sprev + idx) = S;
        const float d = dec[bh * NC + c];
        const float4 z = *(const float4*)(zbuf + idx);
        S.x = S.x * d + z.x; S.y = S.y * d + z.y;
        S.z = S.z * d + z.z; S.w = S.w * d + z.w;
    }
}

// ===== inter-chunk y correction =====
__global__ __launch_bounds__(256) void k_ssd_inter(
    const float* __restrict__ hbc, const float* __restrict__ cum,
    const float* __restrict__ sprev, float* __restrict__ ybuf)
{
    __shared__ float sp[64 * 17];
    __shared__ float cls[QCH * 17];
    __shared__ float cumls[QCH];
    const int bid = blockIdx.x;
    const int c = bid & (NC - 1);
    const int hh = (bid / NC) & (NH - 1);
    const int b = bid / (NC * NH);
    const int m0 = b * T_ + c * QCH;
    const int tid = threadIdx.x;
    {
        const float4 z = *(const float4*)(sprev + bid * 1024 + tid * 4);
        const int p = tid >> 2;
        const int n0 = (tid & 3) * 4;
        sp[p * 17 + n0 + 0] = z.x; sp[p * 17 + n0 + 1] = z.y;
        sp[p * 17 + n0 + 2] = z.z; sp[p * 17 + n0 + 3] = z.w;
    }
    for (int e = tid; e < QCH * 16; e += 256) {
        const int t = e >> 4, n = e & 15;
        cls[t * 17 + n] = hbc[(m0 + t) * CONVDIM + DINNER + NSTATE + n];
    }
    if (tid < QCH) cumls[tid] = cum[(m0 + tid) * NH + hh];
    __syncthreads();
    const int p = tid & 63;
    const int tq = tid >> 6;
    for (int pass = 0; pass < 32; ++pass) {
        const int t = pass * 4 + tq;
        float dot = 0.f;
#pragma unroll
        for (int n = 0; n < 16; ++n) dot += cls[t * 17 + n] * sp[p * 17 + n];
        ybuf[(m0 + t) * DINNER + hh * 64 + p] += __expf(cumls[t]) * dot;
    }
}

// ===== final rmsnorm + partial mean-pool =====
__global__ __launch_bounds__(256) void k_finalnorm_pool(
    const float* __restrict__ h, const float* __restrict__ nfw,
    float* __restrict__ part)
{
    __shared__ float ht[2048];
    __shared__ float red[256];
    __shared__ float rstd[16];
    __shared__ float padd[256];
    const int tile = blockIdx.x & 127;
    const int b = blockIdx.x >> 7;
    const int m0 = b * T_ + tile * 16;
    const int tid = threadIdx.x;
    for (int e = tid; e < 2048; e += 256) ht[e] = h[m0 * DM + e];
    __syncthreads();
    {
        const int tg = tid >> 4, j0 = tid & 15;
        float p = 0.f;
#pragma unroll
        for (int k = 0; k < 8; ++k) { const float v = ht[tg * 128 + j0 + 16 * k]; p += v * v; }
        red[tid] = p;
    }
    __syncthreads();
    if (tid < 16) {
        float s = 0.f;
#pragma unroll
        for (int q = 0; q < 16; ++q) s += red[tid * 16 + q];
        rstd[tid] = rsqrtf(s * (1.f / 128.f) + EPSF);
    }
    __syncthreads();
    const int d = tid & 127, half = tid >> 7;
    float ps = 0.f;
#pragma unroll
    for (int i0 = 0; i0 < 8; ++i0) { const int i = half + 2 * i0; ps += ht[i * 128 + d] * rstd[i]; }
    padd[tid] = ps;
    __syncthreads();
    if (tid < 128) part[(b * 128 + tile) * 128 + tid] = (padd[tid] + padd[128 + tid]) * nfw[tid];
}

// ===== pooled reduce + head GEMM =====
__global__ __launch_bounds__(256) void k_head(
    const float* __restrict__ part, const float* __restrict__ ow,
    const float* __restrict__ ob, float* __restrict__ out)
{
    __shared__ float pooled[128];
    const int b = blockIdx.x;
    const int tid = threadIdx.x;
    if (tid < 128) {
        float s = 0.f;
        for (int tile = 0; tile < 128; ++tile) s += part[(b * 128 + tile) * 128 + tid];
        pooled[tid] = s * (1.f / (float)T_);
    }
    __syncthreads();
    for (int o = tid; o < DIMX; o += 256) {
        float acc = ob[o];
#pragma unroll 4
        for (int d = 0; d < 128; ++d) acc += pooled[d] * ow[d * DIMX + o];
        out[b * DIMX + o] = acc;
    }
}

extern "C" void kernel_launch(void* const* d_in, const int* in_sizes, int n_in,
                              void* d_out, int out_size, void* d_ws, size_t ws_size,
                              hipStream_t stream)
{
    const float* x         = (const float*)d_in[0];
    const float* in_w      = (const float*)d_in[1];
    const float* in_b      = (const float*)d_in[2];
    const float* norm_w    = (const float*)d_in[3];
    const float* inproj_w  = (const float*)d_in[4];
    const float* conv_w    = (const float*)d_in[5];
    const float* conv_b    = (const float*)d_in[6];
    const float* A_log     = (const float*)d_in[7];
    const float* Dvec      = (const float*)d_in[8];
    const float* dt_bias   = (const float*)d_in[9];
    const float* gnorm_w   = (const float*)d_in[10];
    const float* outproj_w = (const float*)d_in[11];
    const float* normf_w   = (const float*)d_in[12];
    const float* out_w     = (const float*)d_in[13];
    const float* out_b     = (const float*)d_in[14];

    float* ws    = (float*)d_ws;
    float* h     = ws + OFF_H;
    float* proj  = ws + OFF_PROJ;
    float* hbc   = ws + OFF_HBC;
    float* ybuf  = ws + OFF_Y;
    float* dtp   = ws + OFF_DTP;
    float* cumb  = ws + OFF_CUM;
    float* zbuf  = ws + OFF_Z;
    float* sprev = ws + OFF_SPREV;
    float* dec   = ws + OFF_DEC;
    float* part  = ws + OFF_PART;
    ushort_t* bf_scr = (ushort_t*)(ws + OFF_BF);     // hn / v (aliased lifetimes)
    ushort_t* wt_in  = (ushort_t*)(ws + OFF_WTIN);   // 128 x 512
    ushort_t* wt_inp = (ushort_t*)(ws + OFF_WTINP);  // 2 x 576 x 128
    ushort_t* wt_out = (ushort_t*)(ws + OFF_WTOUT);  // 2 x 128 x 256

    // one-time (per call) weight transpose+convert — tiny
    k_wt<<<dim3(8, 2), 256, 0, stream>>>(in_w, wt_in, 512, 128, 128);
    for (int l = 0; l < LLAYERS; ++l) {
        k_wt<<<dim3(2, 9), 256, 0, stream>>>(inproj_w + l * DM * PROJ, wt_inp + l * 576 * 128, 128, PROJ, 576);
        k_wt<<<dim3(4, 2), 256, 0, stream>>>(outproj_w + l * DINNER * DM, wt_out + l * 128 * 256, 256, 128, 128);
    }

    // h = x @ in_w + in_b   (A fp32 converted in-stage)
    k_gemm<512, 128, 0, 1, false><<<dim3(MTOK / 64, 2), 256, 0, stream>>>(x, wt_in, in_b, h);

    for (int l = 0; l < LLAYERS; ++l) {
        k_rmsnorm<<<MTOK / 4, 256, 0, stream>>>(h, norm_w + l * DM, bf_scr);
        k_gemm<128, PROJ, PROJ, 0, true><<<dim3(MTOK / 64, 9), 256, 0, stream>>>(
            bf_scr, wt_inp + l * 576 * 128, nullptr, proj);
        k_dtprep<<<B_ * NH * NC, 128, 0, stream>>>(proj, A_log, dt_bias, dtp, cumb, l);
        k_conv<<<(MTOK * CONVDIM) / 256, 256, 0, stream>>>(proj, conv_w, conv_b, hbc, l);
        k_ssd_intra<<<B_ * NH * NC, 256, 0, stream>>>(hbc, dtp, cumb, Dvec, ybuf, zbuf, dec, l);
        k_state_scan<<<B_ * NH, 256, 0, stream>>>(zbuf, dec, sprev);
        k_ssd_inter<<<B_ * NH * NC, 256, 0, stream>>>(hbc, cumb, sprev, ybuf);
        k_gnorm<<<MTOK / 4, 256, 0, stream>>>(ybuf, proj, gnorm_w + l * DINNER, bf_scr);
        k_gemm<256, 128, 0, 2, true><<<dim3(MTOK / 64, 2), 256, 0, stream>>>(
            bf_scr, wt_out + l * 128 * 256, nullptr, h);
    }

    k_finalnorm_pool<<<B_ * (T_ / 16), 256, 0, stream>>>(h, normf_w, part);
    k_head<<<B_, 256, 0, stream>>>(part, out_w, out_b, (float*)d_out);
}

// Round 3
// 328.917 us; speedup vs baseline: 1.7226x; 1.3022x over previous
//
#include <hip/hip_runtime.h>
#include <math.h>

typedef unsigned short ushort_t;
typedef unsigned int uint_t;

// Problem constants
#define B_      8
#define T_      2048
#define DIMX    512
#define DM      128
#define DINNER  256
#define NSTATE  16
#define HDIM    64
#define NH      4
#define CONVDIM 288     // DINNER + 2*NSTATE
#define PROJ    548     // DINNER + CONVDIM + NH
#define KCONV   4
#define LLAYERS 2
#define QCH     128     // chunk length
#define NC      (T_/QCH)  // 16 chunks
#define EPSF    1e-5f
#define MTOK    (B_*T_)   // 16384

// ---- workspace layout (float offsets) ----
#define OFF_H      0u               // 16384*128   = 2097152
#define OFF_PROJ   2097152u         // 16384*548   = 8978432
#define OFF_HBC    11075584u        // 16384*288   = 4718592
#define OFF_Y      15794176u        // 16384*256   = 4194304
#define OFF_DTP    19988480u        // 16384*4     = 65536
#define OFF_CUM    20054016u        // 16384*4     = 65536
#define OFF_Z      20119552u        // 512*1024    = 524288
#define OFF_SPREV  20643840u        // 512*1024    = 524288
#define OFF_DEC    21168128u        // 512
#define OFF_PART   21168640u        // 8*128*128   = 131072
#define OFF_BF     21299712u        // bf16 scratch (hn OR v): 2097152 floats
#define OFF_WTIN   23396864u        // 128x512 bf16 = 32768 floats
#define OFF_WTINP  23429632u        // 2x576x128 bf16 = 73728 floats
#define OFF_WTOUT  23503360u        // 2x128x256 bf16 = 32768 floats
// end 23536128 floats = 94.1 MB

__device__ __forceinline__ ushort_t f2b(float f) {
    uint_t u = __builtin_bit_cast(uint_t, f);
    return (ushort_t)((u + 0x7FFFu + ((u >> 16) & 1u)) >> 16);
}
__device__ __forceinline__ float b2f(ushort_t b) {
    uint_t u = ((uint_t)b) << 16;
    return __builtin_bit_cast(float, u);
}

typedef short bf8 __attribute__((ext_vector_type(8)));
typedef float f4v __attribute__((ext_vector_type(4)));

// ===== weight transpose + bf16 convert: W[K x N] fp32 -> Wt[Npad x K] bf16 =====
__global__ __launch_bounds__(256) void k_wt(
    const float* __restrict__ W, ushort_t* __restrict__ Wt,
    int K, int N, int Npad)
{
    __shared__ float tile[64][65];
    const int k0 = blockIdx.x * 64, n0 = blockIdx.y * 64;
    const int tid = threadIdx.x;
#pragma unroll
    for (int it = 0; it < 16; ++it) {
        const int e = it * 256 + tid;
        const int kk = e >> 6, nn = e & 63;
        tile[kk][nn] = (n0 + nn < N) ? W[(k0 + kk) * N + (n0 + nn)] : 0.f;
    }
    __syncthreads();
#pragma unroll
    for (int it = 0; it < 16; ++it) {
        const int e = it * 256 + tid;
        const int nn = e >> 6, kk = e & 63;
        Wt[(n0 + nn) * K + k0 + kk] = f2b(tile[kk][nn]);
    }
}

// ===== MFMA GEMM: C[M x NGUARD] (ld LDC) = A[M x KTOT] @ Bt^T, 64x64 tile =====
// EPI: 0 = plain, 1 = +bias(aux[col]), 2 = += C in place (residual)
template<int KTOT, int LDC, int NGUARD, int EPI, bool ABF16>
__global__ __launch_bounds__(256) void k_gemm(
    const void* __restrict__ Ap, const ushort_t* __restrict__ Bt,
    const float* __restrict__ aux, float* __restrict__ C)
{
    __shared__ ushort_t Als[64 * 136];
    __shared__ ushort_t Bls[64 * 136];
    const int m0 = blockIdx.x * 64, n0 = blockIdx.y * 64;
    const int tid = threadIdx.x;
    const int lane = tid & 63, w = tid >> 6;
    const int wm = (w >> 1) * 32, wn = (w & 1) * 32;
    const int r16 = lane & 15, q8 = (lane >> 4) * 8;

    f4v acc[2][2];
#pragma unroll
    for (int i = 0; i < 2; ++i)
#pragma unroll
        for (int j = 0; j < 2; ++j) acc[i][j] = (f4v)0.f;

    for (int kc = 0; kc < KTOT; kc += 128) {
        if constexpr (ABF16) {
            const ushort_t* A = (const ushort_t*)Ap;
#pragma unroll
            for (int i = 0; i < 4; ++i) {
                const int e = i * 2048 + tid * 8;
                const int r = e >> 7, c = e & 127;
                *(uint4*)&Als[r * 136 + c] = *(const uint4*)&A[(m0 + r) * KTOT + kc + c];
            }
        } else {
            const float* A = (const float*)Ap;
#pragma unroll
            for (int i = 0; i < 4; ++i) {
                const int e = i * 2048 + tid * 8;
                const int r = e >> 7, c = e & 127;
                const float4 f0 = *(const float4*)&A[(m0 + r) * KTOT + kc + c];
                const float4 f1 = *(const float4*)&A[(m0 + r) * KTOT + kc + c + 4];
                uint4 pk;
                pk.x = (uint_t)f2b(f0.x) | ((uint_t)f2b(f0.y) << 16);
                pk.y = (uint_t)f2b(f0.z) | ((uint_t)f2b(f0.w) << 16);
                pk.z = (uint_t)f2b(f1.x) | ((uint_t)f2b(f1.y) << 16);
                pk.w = (uint_t)f2b(f1.z) | ((uint_t)f2b(f1.w) << 16);
                *(uint4*)&Als[r * 136 + c] = pk;
            }
        }
#pragma unroll
        for (int i = 0; i < 4; ++i) {
            const int e = i * 2048 + tid * 8;
            const int r = e >> 7, c = e & 127;
            *(uint4*)&Bls[r * 136 + c] = *(const uint4*)&Bt[(n0 + r) * KTOT + kc + c];
        }
        __syncthreads();
#pragma unroll
        for (int kk = 0; kk < 128; kk += 32) {
            const bf8 a0 = *(const bf8*)&Als[(wm + r16) * 136 + kk + q8];
            const bf8 a1 = *(const bf8*)&Als[(wm + 16 + r16) * 136 + kk + q8];
            const bf8 b0 = *(const bf8*)&Bls[(wn + r16) * 136 + kk + q8];
            const bf8 b1 = *(const bf8*)&Bls[(wn + 16 + r16) * 136 + kk + q8];
            acc[0][0] = __builtin_amdgcn_mfma_f32_16x16x32_bf16(a0, b0, acc[0][0], 0, 0, 0);
            acc[0][1] = __builtin_amdgcn_mfma_f32_16x16x32_bf16(a0, b1, acc[0][1], 0, 0, 0);
            acc[1][0] = __builtin_amdgcn_mfma_f32_16x16x32_bf16(a1, b0, acc[1][0], 0, 0, 0);
            acc[1][1] = __builtin_amdgcn_mfma_f32_16x16x32_bf16(a1, b1, acc[1][1], 0, 0, 0);
        }
        __syncthreads();
    }
    const int q4 = (lane >> 4) * 4;
#pragma unroll
    for (int i = 0; i < 2; ++i)
#pragma unroll
        for (int j = 0; j < 2; ++j)
#pragma unroll
            for (int r = 0; r < 4; ++r) {
                const int grow = m0 + wm + i * 16 + q4 + r;
                const int gcol = n0 + wn + j * 16 + r16;
                if (NGUARD == 0 || gcol < NGUARD) {
                    float v = acc[i][j][r];
                    if (EPI == 1) v += aux[gcol];
                    if (EPI == 2) v += C[grow * LDC + gcol];
                    C[grow * LDC + gcol] = v;
                }
            }
}

// ===== rmsnorm: h (fp32) -> hn (bf16) =====
__global__ __launch_bounds__(256) void k_rmsnorm(
    const float* __restrict__ h, const float* __restrict__ nw,
    ushort_t* __restrict__ hnb)
{
    const int tk = blockIdx.x * 4 + (threadIdx.x >> 6);
    const int lane = threadIdx.x & 63;
    const float2 v = *(const float2*)&h[tk * 128 + lane * 2];
    float s = v.x * v.x + v.y * v.y;
#pragma unroll
    for (int off = 32; off; off >>= 1) s += __shfl_xor(s, off);
    const float rs = rsqrtf(s * (1.f / 128.f) + EPSF);
    const float a = v.x * rs * nw[lane * 2];
    const float b = v.y * rs * nw[lane * 2 + 1];
    ((uint_t*)hnb)[tk * 64 + lane] = (uint_t)f2b(a) | ((uint_t)f2b(b) << 16);
}

// ===== gated rmsnorm -> bf16 =====
__global__ __launch_bounds__(256) void k_gnorm(
    const float* __restrict__ y, const float* __restrict__ proj,
    const float* __restrict__ gw, ushort_t* __restrict__ vb)
{
    const int tok = blockIdx.x * 4 + (threadIdx.x >> 6);
    const int lane = threadIdx.x & 63;
    const float4 yv = *(const float4*)&y[tok * 256 + lane * 4];
    const float4 g = *(const float4*)&proj[tok * PROJ + lane * 4];
    float4 v;
    v.x = yv.x * (g.x / (1.f + __expf(-g.x)));
    v.y = yv.y * (g.y / (1.f + __expf(-g.y)));
    v.z = yv.z * (g.z / (1.f + __expf(-g.z)));
    v.w = yv.w * (g.w / (1.f + __expf(-g.w)));
    float s = v.x * v.x + v.y * v.y + v.z * v.z + v.w * v.w;
#pragma unroll
    for (int off = 32; off; off >>= 1) s += __shfl_xor(s, off);
    const float rs = rsqrtf(s * (1.f / 256.f) + EPSF);
    const float4 w4 = *(const float4*)&gw[lane * 4];
    uint2 pk;
    pk.x = (uint_t)f2b(v.x * rs * w4.x) | ((uint_t)f2b(v.y * rs * w4.y) << 16);
    pk.y = (uint_t)f2b(v.z * rs * w4.z) | ((uint_t)f2b(v.w * rs * w4.w) << 16);
    ((uint2*)vb)[tok * 64 + lane] = pk;
}

// ===== dt = softplus(raw + bias); per-chunk inclusive cumsum of dt*A =====
__global__ __launch_bounds__(128) void k_dtprep(
    const float* __restrict__ proj, const float* __restrict__ A_log,
    const float* __restrict__ dt_bias, float* __restrict__ dtp,
    float* __restrict__ cum, int l)
{
    __shared__ float sc[128];
    const int bid = blockIdx.x;
    const int c = bid & (NC - 1);
    const int hh = (bid / NC) & (NH - 1);
    const int b = bid / (NC * NH);
    const int t = threadIdx.x;
    const int m = b * T_ + c * QCH + t;
    const float Ah = -expf(A_log[l * NH + hh]);
    const float raw = proj[m * PROJ + DINNER + CONVDIM + hh] + dt_bias[l * NH + hh];
    const float dtv = (raw > 20.f) ? raw : log1pf(expf(raw));
    sc[t] = dtv * Ah;
    __syncthreads();
    for (int off = 1; off < 128; off <<= 1) {
        const float v = (t >= off) ? sc[t - off] : 0.f;
        __syncthreads();
        sc[t] += v;
        __syncthreads();
    }
    dtp[m * NH + hh] = dtv;
    cum[m * NH + hh] = sc[t];
}

// ===== depthwise causal conv (K=4) + silu =====
__global__ __launch_bounds__(256) void k_conv(
    const float* __restrict__ proj, const float* __restrict__ cw,
    const float* __restrict__ cb, float* __restrict__ hbc, int l)
{
    const int e = blockIdx.x * 256 + threadIdx.x;
    if (e >= MTOK * CONVDIM) return;
    const int m = e / CONVDIM;
    const int cch = e - m * CONVDIM;
    const int b = m >> 11;
    const int t = m & (T_ - 1);
    const float* wp = cw + (l * CONVDIM + cch) * KCONV;
    float acc = cb[l * CONVDIM + cch];
#pragma unroll
    for (int k = 0; k < KCONV; ++k) {
        const int tt = t - (KCONV - 1) + k;
        if (tt >= 0) acc += proj[(b * T_ + tt) * PROJ + DINNER + cch] * wp[k];
    }
    hbc[m * CONVDIM + cch] = acc / (1.f + __expf(-acc));
}

// ===== SSD chunk state: Z[p][n] = sum_s x_s[p] * w_s * B_s[n]  (MFMA) =====
__global__ __launch_bounds__(256) void k_ssd_state(
    const float* __restrict__ hbc, const float* __restrict__ dtp,
    const float* __restrict__ cum, float* __restrict__ zbuf,
    float* __restrict__ dec)
{
    __shared__ ushort_t Xt[64 * 136];   // [p][s] bf16
    __shared__ ushort_t wB[16 * 136];   // [n][s] bf16 (w_s * B_s[n])
    __shared__ float cumls[QCH];
    __shared__ float dtls[QCH];
    const int bid = blockIdx.x;
    const int c = bid & (NC - 1);
    const int hh = (bid / NC) & (NH - 1);
    const int b = bid / (NC * NH);
    const int m0 = b * T_ + c * QCH;
    const int tid = threadIdx.x;

    if (tid < QCH) {
        cumls[tid] = cum[(m0 + tid) * NH + hh];
        dtls[tid] = dtp[(m0 + tid) * NH + hh];
    }
    __syncthreads();
    const float clast = cumls[QCH - 1];
    // Xt transpose-stage
    {
        const int p = tid & 63;
        const int s0 = tid >> 6;
#pragma unroll
        for (int pass = 0; pass < 32; ++pass) {
            const int s = s0 + pass * 4;
            Xt[p * 136 + s] = f2b(hbc[(m0 + s) * CONVDIM + hh * 64 + p]);
        }
    }
    // wB
    for (int e = tid; e < QCH * 16; e += 256) {
        const int n = e & 15, s = e >> 4;
        const float w = __expf(clast - cumls[s]) * dtls[s];
        wB[n * 136 + s] = f2b(w * hbc[(m0 + s) * CONVDIM + DINNER + n]);
    }
    __syncthreads();

    const int lane = tid & 63, w = tid >> 6;
    const int r16 = lane & 15, q8 = (lane >> 4) * 8, q4 = (lane >> 4) * 4;
    f4v acc = (f4v)0.f;
#pragma unroll
    for (int kc = 0; kc < 128; kc += 32) {
        const bf8 a = *(const bf8*)&Xt[(w * 16 + r16) * 136 + kc + q8];
        const bf8 bb = *(const bf8*)&wB[r16 * 136 + kc + q8];
        acc = __builtin_amdgcn_mfma_f32_16x16x32_bf16(a, bb, acc, 0, 0, 0);
    }
#pragma unroll
    for (int r = 0; r < 4; ++r) {
        const int p = w * 16 + q4 + r;
        zbuf[bid * 1024 + p * 16 + r16] = acc[r];
    }
    if (tid == 0) dec[bid] = __expf(clast);
}

// ===== inter-chunk state scan =====
__global__ __launch_bounds__(256) void k_state_scan(
    const float* __restrict__ zbuf, const float* __restrict__ dec,
    float* __restrict__ sprev)
{
    const int bh = blockIdx.x;
    const int tid = threadIdx.x;
    float4 S; S.x = 0.f; S.y = 0.f; S.z = 0.f; S.w = 0.f;
    for (int c = 0; c < NC; ++c) {
        const int idx = (bh * NC + c) * 1024 + tid * 4;
        *(float4*)(sprev + idx) = S;
        const float d = dec[bh * NC + c];
        const float4 z = *(const float4*)(zbuf + idx);
        S.x = S.x * d + z.x; S.y = S.y * d + z.y;
        S.z = S.z * d + z.z; S.w = S.w * d + z.w;
    }
}

// ===== fused SSD y: corr(C·Sprev)·exp(cum) + D·x + masked(C·B^T)·X  (MFMA) =====
__global__ __launch_bounds__(256) void k_ssd_y(
    const float* __restrict__ hbc, const float* __restrict__ dtp,
    const float* __restrict__ cum, const float* __restrict__ sprev,
    const float* __restrict__ Dvec, float* __restrict__ ybuf, int l)
{
    __shared__ ushort_t Xt[64 * 136];    // [p][s]
    __shared__ ushort_t BlsT[128 * 40];  // [s][n] k-padded
    __shared__ ushort_t ClsT[128 * 40];  // [t][n] k-padded
    __shared__ ushort_t Gls[128 * 136];  // [t][s]
    __shared__ ushort_t Spt[64 * 40];    // [p][n] k-padded
    __shared__ float cumls[QCH];
    __shared__ float dtls[QCH];
    const int bid = blockIdx.x;
    const int c = bid & (NC - 1);
    const int hh = (bid / NC) & (NH - 1);
    const int b = bid / (NC * NH);
    const int m0 = b * T_ + c * QCH;
    const int tid = threadIdx.x;

    if (tid < QCH) {
        cumls[tid] = cum[(m0 + tid) * NH + hh];
        dtls[tid] = dtp[(m0 + tid) * NH + hh];
    }
    {
        const int p = tid & 63;
        const int s0 = tid >> 6;
#pragma unroll
        for (int pass = 0; pass < 32; ++pass) {
            const int s = s0 + pass * 4;
            Xt[p * 136 + s] = f2b(hbc[(m0 + s) * CONVDIM + hh * 64 + p]);
        }
    }
    for (int e = tid; e < QCH * 16; e += 256) {
        const int n = e & 15, s = e >> 4;
        BlsT[s * 40 + n] = f2b(hbc[(m0 + s) * CONVDIM + DINNER + n]);
        BlsT[s * 40 + 16 + n] = 0;
        ClsT[s * 40 + n] = f2b(hbc[(m0 + s) * CONVDIM + DINNER + NSTATE + n]);
        ClsT[s * 40 + 16 + n] = 0;
    }
    for (int e = tid; e < 1024; e += 256) {
        const int n = e & 15, p = e >> 4;
        Spt[p * 40 + n] = f2b(sprev[bid * 1024 + p * 16 + n]);
        Spt[p * 40 + 16 + n] = 0;
    }
    __syncthreads();

    const int lane = tid & 63, w = tid >> 6;
    const int wrow = w * 32;
    const int r16 = lane & 15, q8 = (lane >> 4) * 8, q4 = (lane >> 4) * 4;
    const float Dh = Dvec[l * NH + hh];

    // a-frags of C (reused for corr + G)
    bf8 cfr[2];
#pragma unroll
    for (int i = 0; i < 2; ++i)
        cfr[i] = *(const bf8*)&ClsT[(wrow + i * 16 + r16) * 40 + q8];

    // cached cum_t / exp(cum_t) for this lane's 8 output rows
    float cumt[8], et[8];
#pragma unroll
    for (int i = 0; i < 2; ++i)
#pragma unroll
        for (int r = 0; r < 4; ++r) {
            const int t = wrow + i * 16 + q4 + r;
            cumt[i * 4 + r] = cumls[t];
            et[i * 4 + r] = __expf(cumls[t]);
        }

    // Phase A: corr = C . Sprev, acc init = exp(cum_t)*corr + Dh*x[t][p]
    f4v acc[2][4];
#pragma unroll
    for (int j = 0; j < 4; ++j) {
        const bf8 sf = *(const bf8*)&Spt[(j * 16 + r16) * 40 + q8];
#pragma unroll
        for (int i = 0; i < 2; ++i) {
            f4v z = (f4v)0.f;
            z = __builtin_amdgcn_mfma_f32_16x16x32_bf16(cfr[i], sf, z, 0, 0, 0);
#pragma unroll
            for (int r = 0; r < 4; ++r) {
                const int t = wrow + i * 16 + q4 + r;
                const int p = j * 16 + r16;
                acc[i][j][r] = z[r] * et[i * 4 + r] + Dh * b2f(Xt[p * 136 + t]);
            }
        }
    }

    // Phase B: G = C . B^T, masked decay, -> Gls (bf16)
#pragma unroll
    for (int ts = 0; ts < 8; ++ts) {
        const bf8 bf = *(const bf8*)&BlsT[(ts * 16 + r16) * 40 + q8];
        const int s = ts * 16 + r16;
        const float cs = cumls[s];
        const float ds = dtls[s];
#pragma unroll
        for (int i = 0; i < 2; ++i) {
            f4v g = (f4v)0.f;
            g = __builtin_amdgcn_mfma_f32_16x16x32_bf16(cfr[i], bf, g, 0, 0, 0);
#pragma unroll
            for (int r = 0; r < 4; ++r) {
                const int t = wrow + i * 16 + q4 + r;
                const float val = (s <= t) ? __expf(cumt[i * 4 + r] - cs) * ds * g[r] : 0.f;
                Gls[t * 136 + s] = f2b(val);
            }
        }
    }
    __syncthreads();

    // Phase C: Y += G @ X  (K = 128)
#pragma unroll
    for (int kc = 0; kc < 128; kc += 32) {
        bf8 af[2];
#pragma unroll
        for (int i = 0; i < 2; ++i)
            af[i] = *(const bf8*)&Gls[(wrow + i * 16 + r16) * 136 + kc + q8];
#pragma unroll
        for (int j = 0; j < 4; ++j) {
            const bf8 xf = *(const bf8*)&Xt[(j * 16 + r16) * 136 + kc + q8];
#pragma unroll
            for (int i = 0; i < 2; ++i)
                acc[i][j] = __builtin_amdgcn_mfma_f32_16x16x32_bf16(af[i], xf, acc[i][j], 0, 0, 0);
        }
    }

    // store
#pragma unroll
    for (int i = 0; i < 2; ++i)
#pragma unroll
        for (int r = 0; r < 4; ++r) {
            const int t = wrow + i * 16 + q4 + r;
#pragma unroll
            for (int j = 0; j < 4; ++j) {
                const int p = j * 16 + r16;
                ybuf[(m0 + t) * DINNER + hh * 64 + p] = acc[i][j][r];
            }
        }
}

// ===== final rmsnorm + partial mean-pool =====
__global__ __launch_bounds__(256) void k_finalnorm_pool(
    const float* __restrict__ h, const float* __restrict__ nfw,
    float* __restrict__ part)
{
    __shared__ float ht[2048];
    __shared__ float red[256];
    __shared__ float rstd[16];
    __shared__ float padd[256];
    const int tile = blockIdx.x & 127;
    const int b = blockIdx.x >> 7;
    const int m0 = b * T_ + tile * 16;
    const int tid = threadIdx.x;
    for (int e = tid; e < 2048; e += 256) ht[e] = h[m0 * DM + e];
    __syncthreads();
    {
        const int tg = tid >> 4, j0 = tid & 15;
        float p = 0.f;
#pragma unroll
        for (int k = 0; k < 8; ++k) { const float v = ht[tg * 128 + j0 + 16 * k]; p += v * v; }
        red[tid] = p;
    }
    __syncthreads();
    if (tid < 16) {
        float s = 0.f;
#pragma unroll
        for (int q = 0; q < 16; ++q) s += red[tid * 16 + q];
        rstd[tid] = rsqrtf(s * (1.f / 128.f) + EPSF);
    }
    __syncthreads();
    const int d = tid & 127, half = tid >> 7;
    float ps = 0.f;
#pragma unroll
    for (int i0 = 0; i0 < 8; ++i0) { const int i = half + 2 * i0; ps += ht[i * 128 + d] * rstd[i]; }
    padd[tid] = ps;
    __syncthreads();
    if (tid < 128) part[(b * 128 + tile) * 128 + tid] = (padd[tid] + padd[128 + tid]) * nfw[tid];
}

// ===== pooled reduce + head GEMM =====
__global__ __launch_bounds__(256) void k_head(
    const float* __restrict__ part, const float* __restrict__ ow,
    const float* __restrict__ ob, float* __restrict__ out)
{
    __shared__ float pooled[128];
    const int b = blockIdx.x;
    const int tid = threadIdx.x;
    if (tid < 128) {
        float s = 0.f;
        for (int tile = 0; tile < 128; ++tile) s += part[(b * 128 + tile) * 128 + tid];
        pooled[tid] = s * (1.f / (float)T_);
    }
    __syncthreads();
    for (int o = tid; o < DIMX; o += 256) {
        float acc = ob[o];
#pragma unroll 4
        for (int d = 0; d < 128; ++d) acc += pooled[d] * ow[d * DIMX + o];
        out[b * DIMX + o] = acc;
    }
}

extern "C" void kernel_launch(void* const* d_in, const int* in_sizes, int n_in,
                              void* d_out, int out_size, void* d_ws, size_t ws_size,
                              hipStream_t stream)
{
    const float* x         = (const float*)d_in[0];
    const float* in_w      = (const float*)d_in[1];
    const float* in_b      = (const float*)d_in[2];
    const float* norm_w    = (const float*)d_in[3];
    const float* inproj_w  = (const float*)d_in[4];
    const float* conv_w    = (const float*)d_in[5];
    const float* conv_b    = (const float*)d_in[6];
    const float* A_log     = (const float*)d_in[7];
    const float* Dvec      = (const float*)d_in[8];
    const float* dt_bias   = (const float*)d_in[9];
    const float* gnorm_w   = (const float*)d_in[10];
    const float* outproj_w = (const float*)d_in[11];
    const float* normf_w   = (const float*)d_in[12];
    const float* out_w     = (const float*)d_in[13];
    const float* out_b     = (const float*)d_in[14];

    float* ws    = (float*)d_ws;
    float* h     = ws + OFF_H;
    float* proj  = ws + OFF_PROJ;
    float* hbc   = ws + OFF_HBC;
    float* ybuf  = ws + OFF_Y;
    float* dtp   = ws + OFF_DTP;
    float* cumb  = ws + OFF_CUM;
    float* zbuf  = ws + OFF_Z;
    float* sprev = ws + OFF_SPREV;
    float* dec   = ws + OFF_DEC;
    float* part  = ws + OFF_PART;
    ushort_t* bf_scr = (ushort_t*)(ws + OFF_BF);
    ushort_t* wt_in  = (ushort_t*)(ws + OFF_WTIN);
    ushort_t* wt_inp = (ushort_t*)(ws + OFF_WTINP);
    ushort_t* wt_out = (ushort_t*)(ws + OFF_WTOUT);

    k_wt<<<dim3(8, 2), 256, 0, stream>>>(in_w, wt_in, 512, 128, 128);
    for (int l = 0; l < LLAYERS; ++l) {
        k_wt<<<dim3(2, 9), 256, 0, stream>>>(inproj_w + l * DM * PROJ, wt_inp + l * 576 * 128, 128, PROJ, 576);
        k_wt<<<dim3(4, 2), 256, 0, stream>>>(outproj_w + l * DINNER * DM, wt_out + l * 128 * 256, 256, 128, 128);
    }

    k_gemm<512, 128, 0, 1, false><<<dim3(MTOK / 64, 2), 256, 0, stream>>>(x, wt_in, in_b, h);

    for (int l = 0; l < LLAYERS; ++l) {
        k_rmsnorm<<<MTOK / 4, 256, 0, stream>>>(h, norm_w + l * DM, bf_scr);
        k_gemm<128, PROJ, PROJ, 0, true><<<dim3(MTOK / 64, 9), 256, 0, stream>>>(
            bf_scr, wt_inp + l * 576 * 128, nullptr, proj);
        k_dtprep<<<B_ * NH * NC, 128, 0, stream>>>(proj, A_log, dt_bias, dtp, cumb, l);
        k_conv<<<(MTOK * CONVDIM) / 256, 256, 0, stream>>>(proj, conv_w, conv_b, hbc, l);
        k_ssd_state<<<B_ * NH * NC, 256, 0, stream>>>(hbc, dtp, cumb, zbuf, dec);
        k_state_scan<<<B_ * NH, 256, 0, stream>>>(zbuf, dec, sprev);
        k_ssd_y<<<B_ * NH * NC, 256, 0, stream>>>(hbc, dtp, cumb, sprev, Dvec, ybuf, l);
        k_gnorm<<<MTOK / 4, 256, 0, stream>>>(ybuf, proj, gnorm_w + l * DINNER, bf_scr);
        k_gemm<256, 128, 0, 2, true><<<dim3(MTOK / 64, 2), 256, 0, stream>>>(
            bf_scr, wt_out + l * 128 * 256, nullptr, h);
    }

    k_finalnorm_pool<<<B_ * (T_ / 16), 256, 0, stream>>>(h, normf_w, part);
    k_head<<<B_, 256, 0, stream>>>(part, out_w, out_b, (float*)d_out);
}

// Round 8
// 315.024 us; speedup vs baseline: 1.7985x; 1.0441x over previous
//
#include <hip/hip_runtime.h>
#include <math.h>

typedef unsigned short ushort_t;
typedef unsigned int uint_t;

// Problem constants
#define B_      8
#define T_      2048
#define DIMX    512
#define DM      128
#define DINNER  256
#define NSTATE  16
#define HDIM    64
#define NH      4
#define CONVDIM 288
#define PROJ    548
#define KCONV   4
#define LLAYERS 2
#define QCH     128
#define NC      (T_/QCH)
#define EPSF    1e-5f
#define MTOK    (B_*T_)

// ---- workspace layout (float offsets) — identical to round-3 passing build ----
#define OFF_H      0u
#define OFF_PROJ   2097152u
#define OFF_HBC    11075584u
#define OFF_Y      15794176u
#define OFF_DTP    19988480u
#define OFF_CUM    20054016u
#define OFF_Z      20119552u
#define OFF_SPREV  20643840u
#define OFF_DEC    21168128u
#define OFF_PART   21168640u
#define OFF_BF     21299712u
#define OFF_WTIN   23396864u
#define OFF_WTINP  23429632u
#define OFF_WTOUT  23503360u

__device__ __forceinline__ ushort_t f2b(float f) {
    uint_t u = __builtin_bit_cast(uint_t, f);
    return (ushort_t)((u + 0x7FFFu + ((u >> 16) & 1u)) >> 16);
}
__device__ __forceinline__ float b2f(ushort_t b) {
    uint_t u = ((uint_t)b) << 16;
    return __builtin_bit_cast(float, u);
}

typedef short bf8 __attribute__((ext_vector_type(8)));
typedef float f4v __attribute__((ext_vector_type(4)));

// ===== ONLY delta vs round-3: all weight transposes in ONE kernel =====
__global__ __launch_bounds__(256) void k_wt_all(
    const float* __restrict__ in_w, const float* __restrict__ inproj_w,
    const float* __restrict__ outproj_w,
    ushort_t* __restrict__ wt_in, ushort_t* __restrict__ wt_inp,
    ushort_t* __restrict__ wt_out)
{
    __shared__ float tile[64][65];
    int idx = blockIdx.x;
    const float* W; ushort_t* Wt; int K, N, k0, n0;
    if (idx < 16) {
        W = in_w; Wt = wt_in; K = 512; N = 128;
        k0 = (idx & 7) * 64; n0 = (idx >> 3) * 64;
    } else if (idx < 52) {
        int r = idx - 16; int l = r / 18; r -= l * 18;
        W = inproj_w + l * 128 * PROJ; Wt = wt_inp + l * 576 * 128; K = 128; N = PROJ;
        k0 = (r & 1) * 64; n0 = (r >> 1) * 64;
    } else {
        int r = idx - 52; int l = r / 8; r -= l * 8;
        W = outproj_w + l * 256 * 128; Wt = wt_out + l * 128 * 256; K = 256; N = 128;
        k0 = (r & 3) * 64; n0 = (r >> 2) * 64;
    }
    const int tid = threadIdx.x;
#pragma unroll
    for (int it = 0; it < 16; ++it) {
        const int e = it * 256 + tid;
        const int kk = e >> 6, nn = e & 63;
        tile[kk][nn] = (n0 + nn < N) ? W[(k0 + kk) * N + (n0 + nn)] : 0.f;
    }
    __syncthreads();
#pragma unroll
    for (int it = 0; it < 16; ++it) {
        const int e = it * 256 + tid;
        const int nn = e >> 6, kk = e & 63;
        Wt[(n0 + nn) * K + k0 + kk] = f2b(tile[kk][nn]);
    }
}

// ===== MFMA GEMM: C[M x NGUARD] (ld LDC) = A[M x KTOT] @ Bt^T, 64x64 tile =====
// EPI: 0 = plain, 1 = +bias(aux[col]), 2 = += C in place (residual)
template<int KTOT, int LDC, int NGUARD, int EPI, bool ABF16>
__global__ __launch_bounds__(256) void k_gemm(
    const void* __restrict__ Ap, const ushort_t* __restrict__ Bt,
    const float* __restrict__ aux, float* __restrict__ C)
{
    __shared__ ushort_t Als[64 * 136];
    __shared__ ushort_t Bls[64 * 136];
    const int m0 = blockIdx.x * 64, n0 = blockIdx.y * 64;
    const int tid = threadIdx.x;
    const int lane = tid & 63, w = tid >> 6;
    const int wm = (w >> 1) * 32, wn = (w & 1) * 32;
    const int r16 = lane & 15, q8 = (lane >> 4) * 8;

    f4v acc[2][2];
#pragma unroll
    for (int i = 0; i < 2; ++i)
#pragma unroll
        for (int j = 0; j < 2; ++j) acc[i][j] = (f4v)0.f;

    for (int kc = 0; kc < KTOT; kc += 128) {
        if constexpr (ABF16) {
            const ushort_t* A = (const ushort_t*)Ap;
#pragma unroll
            for (int i = 0; i < 4; ++i) {
                const int e = i * 2048 + tid * 8;
                const int r = e >> 7, c = e & 127;
                *(uint4*)&Als[r * 136 + c] = *(const uint4*)&A[(m0 + r) * KTOT + kc + c];
            }
        } else {
            const float* A = (const float*)Ap;
#pragma unroll
            for (int i = 0; i < 4; ++i) {
                const int e = i * 2048 + tid * 8;
                const int r = e >> 7, c = e & 127;
                const float4 f0 = *(const float4*)&A[(m0 + r) * KTOT + kc + c];
                const float4 f1 = *(const float4*)&A[(m0 + r) * KTOT + kc + c + 4];
                uint4 pk;
                pk.x = (uint_t)f2b(f0.x) | ((uint_t)f2b(f0.y) << 16);
                pk.y = (uint_t)f2b(f0.z) | ((uint_t)f2b(f0.w) << 16);
                pk.z = (uint_t)f2b(f1.x) | ((uint_t)f2b(f1.y) << 16);
                pk.w = (uint_t)f2b(f1.z) | ((uint_t)f2b(f1.w) << 16);
                *(uint4*)&Als[r * 136 + c] = pk;
            }
        }
#pragma unroll
        for (int i = 0; i < 4; ++i) {
            const int e = i * 2048 + tid * 8;
            const int r = e >> 7, c = e & 127;
            *(uint4*)&Bls[r * 136 + c] = *(const uint4*)&Bt[(n0 + r) * KTOT + kc + c];
        }
        __syncthreads();
#pragma unroll
        for (int kk = 0; kk < 128; kk += 32) {
            const bf8 a0 = *(const bf8*)&Als[(wm + r16) * 136 + kk + q8];
            const bf8 a1 = *(const bf8*)&Als[(wm + 16 + r16) * 136 + kk + q8];
            const bf8 b0 = *(const bf8*)&Bls[(wn + r16) * 136 + kk + q8];
            const bf8 b1 = *(const bf8*)&Bls[(wn + 16 + r16) * 136 + kk + q8];
            acc[0][0] = __builtin_amdgcn_mfma_f32_16x16x32_bf16(a0, b0, acc[0][0], 0, 0, 0);
            acc[0][1] = __builtin_amdgcn_mfma_f32_16x16x32_bf16(a0, b1, acc[0][1], 0, 0, 0);
            acc[1][0] = __builtin_amdgcn_mfma_f32_16x16x32_bf16(a1, b0, acc[1][0], 0, 0, 0);
            acc[1][1] = __builtin_amdgcn_mfma_f32_16x16x32_bf16(a1, b1, acc[1][1], 0, 0, 0);
        }
        __syncthreads();
    }
    const int q4 = (lane >> 4) * 4;
#pragma unroll
    for (int i = 0; i < 2; ++i)
#pragma unroll
        for (int j = 0; j < 2; ++j)
#pragma unroll
            for (int r = 0; r < 4; ++r) {
                const int grow = m0 + wm + i * 16 + q4 + r;
                const int gcol = n0 + wn + j * 16 + r16;
                if (NGUARD == 0 || gcol < NGUARD) {
                    float v = acc[i][j][r];
                    if (EPI == 1) v += aux[gcol];
                    if (EPI == 2) v += C[grow * LDC + gcol];
                    C[grow * LDC + gcol] = v;
                }
            }
}

// ===== rmsnorm: h (fp32) -> hn (bf16) =====
__global__ __launch_bounds__(256) void k_rmsnorm(
    const float* __restrict__ h, const float* __restrict__ nw,
    ushort_t* __restrict__ hnb)
{
    const int tk = blockIdx.x * 4 + (threadIdx.x >> 6);
    const int lane = threadIdx.x & 63;
    const float2 v = *(const float2*)&h[tk * 128 + lane * 2];
    float s = v.x * v.x + v.y * v.y;
#pragma unroll
    for (int off = 32; off; off >>= 1) s += __shfl_xor(s, off);
    const float rs = rsqrtf(s * (1.f / 128.f) + EPSF);
    const float a = v.x * rs * nw[lane * 2];
    const float b = v.y * rs * nw[lane * 2 + 1];
    ((uint_t*)hnb)[tk * 64 + lane] = (uint_t)f2b(a) | ((uint_t)f2b(b) << 16);
}

// ===== gated rmsnorm -> bf16 =====
__global__ __launch_bounds__(256) void k_gnorm(
    const float* __restrict__ y, const float* __restrict__ proj,
    const float* __restrict__ gw, ushort_t* __restrict__ vb)
{
    const int tok = blockIdx.x * 4 + (threadIdx.x >> 6);
    const int lane = threadIdx.x & 63;
    const float4 yv = *(const float4*)&y[tok * 256 + lane * 4];
    const float4 g = *(const float4*)&proj[tok * PROJ + lane * 4];
    float4 v;
    v.x = yv.x * (g.x / (1.f + __expf(-g.x)));
    v.y = yv.y * (g.y / (1.f + __expf(-g.y)));
    v.z = yv.z * (g.z / (1.f + __expf(-g.z)));
    v.w = yv.w * (g.w / (1.f + __expf(-g.w)));
    float s = v.x * v.x + v.y * v.y + v.z * v.z + v.w * v.w;
#pragma unroll
    for (int off = 32; off; off >>= 1) s += __shfl_xor(s, off);
    const float rs = rsqrtf(s * (1.f / 256.f) + EPSF);
    const float4 w4 = *(const float4*)&gw[lane * 4];
    uint2 pk;
    pk.x = (uint_t)f2b(v.x * rs * w4.x) | ((uint_t)f2b(v.y * rs * w4.y) << 16);
    pk.y = (uint_t)f2b(v.z * rs * w4.z) | ((uint_t)f2b(v.w * rs * w4.w) << 16);
    ((uint2*)vb)[tok * 64 + lane] = pk;
}

// ===== dt = softplus(raw + bias); per-chunk inclusive cumsum of dt*A =====
__global__ __launch_bounds__(128) void k_dtprep(
    const float* __restrict__ proj, const float* __restrict__ A_log,
    const float* __restrict__ dt_bias, float* __restrict__ dtp,
    float* __restrict__ cum, int l)
{
    __shared__ float sc[128];
    const int bid = blockIdx.x;
    const int c = bid & (NC - 1);
    const int hh = (bid / NC) & (NH - 1);
    const int b = bid / (NC * NH);
    const int t = threadIdx.x;
    const int m = b * T_ + c * QCH + t;
    const float Ah = -expf(A_log[l * NH + hh]);
    const float raw = proj[m * PROJ + DINNER + CONVDIM + hh] + dt_bias[l * NH + hh];
    const float dtv = (raw > 20.f) ? raw : log1pf(expf(raw));
    sc[t] = dtv * Ah;
    __syncthreads();
    for (int off = 1; off < 128; off <<= 1) {
        const float v = (t >= off) ? sc[t - off] : 0.f;
        __syncthreads();
        sc[t] += v;
        __syncthreads();
    }
    dtp[m * NH + hh] = dtv;
    cum[m * NH + hh] = sc[t];
}

// ===== depthwise causal conv (K=4) + silu =====
__global__ __launch_bounds__(256) void k_conv(
    const float* __restrict__ proj, const float* __restrict__ cw,
    const float* __restrict__ cb, float* __restrict__ hbc, int l)
{
    const int e = blockIdx.x * 256 + threadIdx.x;
    if (e >= MTOK * CONVDIM) return;
    const int m = e / CONVDIM;
    const int cch = e - m * CONVDIM;
    const int b = m >> 11;
    const int t = m & (T_ - 1);
    const float* wp = cw + (l * CONVDIM + cch) * KCONV;
    float acc = cb[l * CONVDIM + cch];
#pragma unroll
    for (int k = 0; k < KCONV; ++k) {
        const int tt = t - (KCONV - 1) + k;
        if (tt >= 0) acc += proj[(b * T_ + tt) * PROJ + DINNER + cch] * wp[k];
    }
    hbc[m * CONVDIM + cch] = acc / (1.f + __expf(-acc));
}

// ===== SSD chunk state: Z[p][n] = sum_s x_s[p] * w_s * B_s[n]  (MFMA) =====
__global__ __launch_bounds__(256) void k_ssd_state(
    const float* __restrict__ hbc, const float* __restrict__ dtp,
    const float* __restrict__ cum, float* __restrict__ zbuf,
    float* __restrict__ dec)
{
    __shared__ ushort_t Xt[64 * 136];   // [p][s] bf16
    __shared__ ushort_t wB[16 * 136];   // [n][s] bf16 (w_s * B_s[n])
    __shared__ float cumls[QCH];
    __shared__ float dtls[QCH];
    const int bid = blockIdx.x;
    const int c = bid & (NC - 1);
    const int hh = (bid / NC) & (NH - 1);
    const int b = bid / (NC * NH);
    const int m0 = b * T_ + c * QCH;
    const int tid = threadIdx.x;

    if (tid < QCH) {
        cumls[tid] = cum[(m0 + tid) * NH + hh];
        dtls[tid] = dtp[(m0 + tid) * NH + hh];
    }
    __syncthreads();
    const float clast = cumls[QCH - 1];
    // Xt transpose-stage
    {
        const int p = tid & 63;
        const int s0 = tid >> 6;
#pragma unroll
        for (int pass = 0; pass < 32; ++pass) {
            const int s = s0 + pass * 4;
            Xt[p * 136 + s] = f2b(hbc[(m0 + s) * CONVDIM + hh * 64 + p]);
        }
    }
    // wB
    for (int e = tid; e < QCH * 16; e += 256) {
        const int n = e & 15, s = e >> 4;
        const float w = __expf(clast - cumls[s]) * dtls[s];
        wB[n * 136 + s] = f2b(w * hbc[(m0 + s) * CONVDIM + DINNER + n]);
    }
    __syncthreads();

    const int lane = tid & 63, w = tid >> 6;
    const int r16 = lane & 15, q8 = (lane >> 4) * 8, q4 = (lane >> 4) * 4;
    f4v acc = (f4v)0.f;
#pragma unroll
    for (int kc = 0; kc < 128; kc += 32) {
        const bf8 a = *(const bf8*)&Xt[(w * 16 + r16) * 136 + kc + q8];
        const bf8 bb = *(const bf8*)&wB[r16 * 136 + kc + q8];
        acc = __builtin_amdgcn_mfma_f32_16x16x32_bf16(a, bb, acc, 0, 0, 0);
    }
#pragma unroll
    for (int r = 0; r < 4; ++r) {
        const int p = w * 16 + q4 + r;
        zbuf[bid * 1024 + p * 16 + r16] = acc[r];
    }
    if (tid == 0) dec[bid] = __expf(clast);
}

// ===== inter-chunk state scan =====
__global__ __launch_bounds__(256) void k_state_scan(
    const float* __restrict__ zbuf, const float* __restrict__ dec,
    float* __restrict__ sprev)
{
    const int bh = blockIdx.x;
    const int tid = threadIdx.x;
    float4 S; S.x = 0.f; S.y = 0.f; S.z = 0.f; S.w = 0.f;
    for (int c = 0; c < NC; ++c) {
        const int idx = (bh * NC + c) * 1024 + tid * 4;
        *(float4*)(sprev + idx) = S;
        const float d = dec[bh * NC + c];
        const float4 z = *(const float4*)(zbuf + idx);
        S.x = S.x * d + z.x; S.y = S.y * d + z.y;
        S.z = S.z * d + z.z; S.w = S.w * d + z.w;
    }
}

// ===== fused SSD y: corr(C·Sprev)·exp(cum) + D·x + masked(C·B^T)·X  (MFMA) =====
__global__ __launch_bounds__(256) void k_ssd_y(
    const float* __restrict__ hbc, const float* __restrict__ dtp,
    const float* __restrict__ cum, const float* __restrict__ sprev,
    const float* __restrict__ Dvec, float* __restrict__ ybuf, int l)
{
    __shared__ ushort_t Xt[64 * 136];    // [p][s]
    __shared__ ushort_t BlsT[128 * 40];  // [s][n] k-padded
    __shared__ ushort_t ClsT[128 * 40];  // [t][n] k-padded
    __shared__ ushort_t Gls[128 * 136];  // [t][s]
    __shared__ ushort_t Spt[64 * 40];    // [p][n] k-padded
    __shared__ float cumls[QCH];
    __shared__ float dtls[QCH];
    const int bid = blockIdx.x;
    const int c = bid & (NC - 1);
    const int hh = (bid / NC) & (NH - 1);
    const int b = bid / (NC * NH);
    const int m0 = b * T_ + c * QCH;
    const int tid = threadIdx.x;

    if (tid < QCH) {
        cumls[tid] = cum[(m0 + tid) * NH + hh];
        dtls[tid] = dtp[(m0 + tid) * NH + hh];
    }
    {
        const int p = tid & 63;
        const int s0 = tid >> 6;
#pragma unroll
        for (int pass = 0; pass < 32; ++pass) {
            const int s = s0 + pass * 4;
            Xt[p * 136 + s] = f2b(hbc[(m0 + s) * CONVDIM + hh * 64 + p]);
        }
    }
    for (int e = tid; e < QCH * 16; e += 256) {
        const int n = e & 15, s = e >> 4;
        BlsT[s * 40 + n] = f2b(hbc[(m0 + s) * CONVDIM + DINNER + n]);
        BlsT[s * 40 + 16 + n] = 0;
        ClsT[s * 40 + n] = f2b(hbc[(m0 + s) * CONVDIM + DINNER + NSTATE + n]);
        ClsT[s * 40 + 16 + n] = 0;
    }
    for (int e = tid; e < 1024; e += 256) {
        const int n = e & 15, p = e >> 4;
        Spt[p * 40 + n] = f2b(sprev[bid * 1024 + p * 16 + n]);
        Spt[p * 40 + 16 + n] = 0;
    }
    __syncthreads();

    const int lane = tid & 63, w = tid >> 6;
    const int wrow = w * 32;
    const int r16 = lane & 15, q8 = (lane >> 4) * 8, q4 = (lane >> 4) * 4;
    const float Dh = Dvec[l * NH + hh];

    // a-frags of C (reused for corr + G)
    bf8 cfr[2];
#pragma unroll
    for (int i = 0; i < 2; ++i)
        cfr[i] = *(const bf8*)&ClsT[(wrow + i * 16 + r16) * 40 + q8];

    float cumt[8], et[8];
#pragma unroll
    for (int i = 0; i < 2; ++i)
#pragma unroll
        for (int r = 0; r < 4; ++r) {
            const int t = wrow + i * 16 + q4 + r;
            cumt[i * 4 + r] = cumls[t];
            et[i * 4 + r] = __expf(cumls[t]);
        }

    // Phase A: corr = C . Sprev, acc init = exp(cum_t)*corr + Dh*x[t][p]
    f4v acc[2][4];
#pragma unroll
    for (int j = 0; j < 4; ++j) {
        const bf8 sf = *(const bf8*)&Spt[(j * 16 + r16) * 40 + q8];
#pragma unroll
        for (int i = 0; i < 2; ++i) {
            f4v z = (f4v)0.f;
            z = __builtin_amdgcn_mfma_f32_16x16x32_bf16(cfr[i], sf, z, 0, 0, 0);
#pragma unroll
            for (int r = 0; r < 4; ++r) {
                const int t = wrow + i * 16 + q4 + r;
                const int p = j * 16 + r16;
                acc[i][j][r] = z[r] * et[i * 4 + r] + Dh * b2f(Xt[p * 136 + t]);
            }
        }
    }

    // Phase B: G = C . B^T, masked decay, -> Gls (bf16)
#pragma unroll
    for (int ts = 0; ts < 8; ++ts) {
        const bf8 bf = *(const bf8*)&BlsT[(ts * 16 + r16) * 40 + q8];
        const int s = ts * 16 + r16;
        const float cs = cumls[s];
        const float ds = dtls[s];
#pragma unroll
        for (int i = 0; i < 2; ++i) {
            f4v g = (f4v)0.f;
            g = __builtin_amdgcn_mfma_f32_16x16x32_bf16(cfr[i], bf, g, 0, 0, 0);
#pragma unroll
            for (int r = 0; r < 4; ++r) {
                const int t = wrow + i * 16 + q4 + r;
                const float val = (s <= t) ? __expf(cumt[i * 4 + r] - cs) * ds * g[r] : 0.f;
                Gls[t * 136 + s] = f2b(val);
            }
        }
    }
    __syncthreads();

    // Phase C: Y += G @ X  (K = 128)
#pragma unroll
    for (int kc = 0; kc < 128; kc += 32) {
        bf8 af[2];
#pragma unroll
        for (int i = 0; i < 2; ++i)
            af[i] = *(const bf8*)&Gls[(wrow + i * 16 + r16) * 136 + kc + q8];
#pragma unroll
        for (int j = 0; j < 4; ++j) {
            const bf8 xf = *(const bf8*)&Xt[(j * 16 + r16) * 136 + kc + q8];
#pragma unroll
            for (int i = 0; i < 2; ++i)
                acc[i][j] = __builtin_amdgcn_mfma_f32_16x16x32_bf16(af[i], xf, acc[i][j], 0, 0, 0);
        }
    }

    // store
#pragma unroll
    for (int i = 0; i < 2; ++i)
#pragma unroll
        for (int r = 0; r < 4; ++r) {
            const int t = wrow + i * 16 + q4 + r;
#pragma unroll
            for (int j = 0; j < 4; ++j) {
                const int p = j * 16 + r16;
                ybuf[(m0 + t) * DINNER + hh * 64 + p] = acc[i][j][r];
            }
        }
}

// ===== final rmsnorm + partial mean-pool =====
__global__ __launch_bounds__(256) void k_finalnorm_pool(
    const float* __restrict__ h, const float* __restrict__ nfw,
    float* __restrict__ part)
{
    __shared__ float ht[2048];
    __shared__ float red[256];
    __shared__ float rstd[16];
    __shared__ float padd[256];
    const int tile = blockIdx.x & 127;
    const int b = blockIdx.x >> 7;
    const int m0 = b * T_ + tile * 16;
    const int tid = threadIdx.x;
    for (int e = tid; e < 2048; e += 256) ht[e] = h[m0 * DM + e];
    __syncthreads();
    {
        const int tg = tid >> 4, j0 = tid & 15;
        float p = 0.f;
#pragma unroll
        for (int k = 0; k < 8; ++k) { const float v = ht[tg * 128 + j0 + 16 * k]; p += v * v; }
        red[tid] = p;
    }
    __syncthreads();
    if (tid < 16) {
        float s = 0.f;
#pragma unroll
        for (int q = 0; q < 16; ++q) s += red[tid * 16 + q];
        rstd[tid] = rsqrtf(s * (1.f / 128.f) + EPSF);
    }
    __syncthreads();
    const int d = tid & 127, half = tid >> 7;
    float ps = 0.f;
#pragma unroll
    for (int i0 = 0; i0 < 8; ++i0) { const int i = half + 2 * i0; ps += ht[i * 128 + d] * rstd[i]; }
    padd[tid] = ps;
    __syncthreads();
    if (tid < 128) part[(b * 128 + tile) * 128 + tid] = (padd[tid] + padd[128 + tid]) * nfw[tid];
}

// ===== pooled reduce + head GEMM =====
__global__ __launch_bounds__(256) void k_head(
    const float* __restrict__ part, const float* __restrict__ ow,
    const float* __restrict__ ob, float* __restrict__ out)
{
    __shared__ float pooled[128];
    const int b = blockIdx.x;
    const int tid = threadIdx.x;
    if (tid < 128) {
        float s = 0.f;
        for (int tile = 0; tile < 128; ++tile) s += part[(b * 128 + tile) * 128 + tid];
        pooled[tid] = s * (1.f / (float)T_);
    }
    __syncthreads();
    for (int o = tid; o < DIMX; o += 256) {
        float acc = ob[o];
#pragma unroll 4
        for (int d = 0; d < 128; ++d) acc += pooled[d] * ow[d * DIMX + o];
        out[b * DIMX + o] = acc;
    }
}

extern "C" void kernel_launch(void* const* d_in, const int* in_sizes, int n_in,
                              void* d_out, int out_size, void* d_ws, size_t ws_size,
                              hipStream_t stream)
{
    const float* x         = (const float*)d_in[0];
    const float* in_w      = (const float*)d_in[1];
    const float* in_b      = (const float*)d_in[2];
    const float* norm_w    = (const float*)d_in[3];
    const float* inproj_w  = (const float*)d_in[4];
    const float* conv_w    = (const float*)d_in[5];
    const float* conv_b    = (const float*)d_in[6];
    const float* A_log     = (const float*)d_in[7];
    const float* Dvec      = (const float*)d_in[8];
    const float* dt_bias   = (const float*)d_in[9];
    const float* gnorm_w   = (const float*)d_in[10];
    const float* outproj_w = (const float*)d_in[11];
    const float* normf_w   = (const float*)d_in[12];
    const float* out_w     = (const float*)d_in[13];
    const float* out_b     = (const float*)d_in[14];

    float* ws    = (float*)d_ws;
    float* h     = ws + OFF_H;
    float* proj  = ws + OFF_PROJ;
    float* hbc   = ws + OFF_HBC;
    float* ybuf  = ws + OFF_Y;
    float* dtp   = ws + OFF_DTP;
    float* cumb  = ws + OFF_CUM;
    float* zbuf  = ws + OFF_Z;
    float* sprev = ws + OFF_SPREV;
    float* dec   = ws + OFF_DEC;
    float* part  = ws + OFF_PART;
    ushort_t* bf_scr = (ushort_t*)(ws + OFF_BF);
    ushort_t* wt_in  = (ushort_t*)(ws + OFF_WTIN);
    ushort_t* wt_inp = (ushort_t*)(ws + OFF_WTINP);
    ushort_t* wt_out = (ushort_t*)(ws + OFF_WTOUT);

    k_wt_all<<<68, 256, 0, stream>>>(in_w, inproj_w, outproj_w, wt_in, wt_inp, wt_out);

    k_gemm<512, 128, 0, 1, false><<<dim3(MTOK / 64, 2), 256, 0, stream>>>(x, wt_in, in_b, h);

    for (int l = 0; l < LLAYERS; ++l) {
        k_rmsnorm<<<MTOK / 4, 256, 0, stream>>>(h, norm_w + l * DM, bf_scr);
        k_gemm<128, PROJ, PROJ, 0, true><<<dim3(MTOK / 64, 9), 256, 0, stream>>>(
            bf_scr, wt_inp + l * 576 * 128, nullptr, proj);
        k_dtprep<<<B_ * NH * NC, 128, 0, stream>>>(proj, A_log, dt_bias, dtp, cumb, l);
        k_conv<<<(MTOK * CONVDIM) / 256, 256, 0, stream>>>(proj, conv_w, conv_b, hbc, l);
        k_ssd_state<<<B_ * NH * NC, 256, 0, stream>>>(hbc, dtp, cumb, zbuf, dec);
        k_state_scan<<<B_ * NH, 256, 0, stream>>>(zbuf, dec, sprev);
        k_ssd_y<<<B_ * NH * NC, 256, 0, stream>>>(hbc, dtp, cumb, sprev, Dvec, ybuf, l);
        k_gnorm<<<MTOK / 4, 256, 0, stream>>>(ybuf, proj, gnorm_w + l * DINNER, bf_scr);
        k_gemm<256, 128, 0, 2, true><<<dim3(MTOK / 64, 2), 256, 0, stream>>>(
            bf_scr, wt_out + l * 128 * 256, nullptr, h);
    }

    k_finalnorm_pool<<<B_ * (T_ / 16), 256, 0, stream>>>(h, normf_w, part);
    k_head<<<B_, 256, 0, stream>>>(part, out_w, out_b, (float*)d_out);
}